// Round 18
// baseline (118.854 us; speedup 1.0000x reference)
//
#include <hip/hip_runtime.h>
#include <hip/hip_bf16.h>
#include <float.h>
#include <math.h>

// Problem constants: B=2, L=2048, D=1024, NH=16, HD=64
#define BB  2
#define LLEN 2048
#define DD  1024
#define NHH 16
#define HDD 64
#define MROWS (BB * LLEN)   // 4096

typedef __bf16 bf16x8  __attribute__((ext_vector_type(8)));
typedef float  f32x4   __attribute__((ext_vector_type(4)));
typedef float  f32x16  __attribute__((ext_vector_type(16)));
typedef ushort us8     __attribute__((ext_vector_type(8)));

#define EXP2F(x) __builtin_amdgcn_exp2f(x)   // 1-inst v_exp_f32

static __device__ __forceinline__ ushort f2bf(float f) {
    __hip_bfloat16 h = __float2bfloat16(f);
    return *reinterpret_cast<ushort*>(&h);
}
static __device__ __forceinline__ unsigned pack2(float a, float b) {
    return (unsigned)f2bf(a) | ((unsigned)f2bf(b) << 16);
}

__device__ __forceinline__ void gload16(const void* g, void* l) {
    __builtin_amdgcn_global_load_lds(
        (const __attribute__((address_space(1))) void*)g,
        (__attribute__((address_space(3))) void*)l, 16, 0, 0);
}

// ---------------------------------------------------------------------------
// x fp32 -> bf16, 4 elems/thread
// ---------------------------------------------------------------------------
__global__ __launch_bounds__(256) void cvt_x_k(const float* __restrict__ in,
                                               ushort* __restrict__ out) {
    int idx = blockIdx.x * 256 + threadIdx.x;
    float4 v = reinterpret_cast<const float4*>(in)[idx];
    ushort4 o;
    o.x = f2bf(v.x); o.y = f2bf(v.y); o.z = f2bf(v.z); o.w = f2bf(v.w);
    reinterpret_cast<ushort4*>(out)[idx] = o;
}

// ---------------------------------------------------------------------------
// All 4 weight transposes+converts in one launch: fp32 [1024][1024] -> bf16 [N][K]
// ---------------------------------------------------------------------------
__global__ __launch_bounds__(256) void wt_cvt_all_k(const float* __restrict__ w0,
                                                    const float* __restrict__ w1,
                                                    const float* __restrict__ w2,
                                                    const float* __restrict__ w3,
                                                    ushort* __restrict__ qkv,
                                                    ushort* __restrict__ wo) {
    __shared__ float T[64][65];
    const int z = blockIdx.z;
    const float* in = (z == 0) ? w0 : (z == 1) ? w1 : (z == 2) ? w2 : w3;
    ushort* out = (z < 3) ? (qkv + (size_t)z * 1024 * DD) : wo;

    const int r0 = blockIdx.y * 64, c0 = blockIdx.x * 64;
    const int tid = threadIdx.x;
    for (int i = tid; i < 64 * 16; i += 256) {
        int r = i >> 4, c4 = (i & 15) * 4;
        float4 v = *reinterpret_cast<const float4*>(&in[(size_t)(r0 + r) * DD + c0 + c4]);
        T[r][c4 + 0] = v.x; T[r][c4 + 1] = v.y; T[r][c4 + 2] = v.z; T[r][c4 + 3] = v.w;
    }
    __syncthreads();
    for (int i = tid; i < 64 * 16; i += 256) {
        int rr = i >> 4, cc4 = (i & 15) * 4;
        ushort4 o;
        o.x = f2bf(T[cc4 + 0][rr]);
        o.y = f2bf(T[cc4 + 1][rr]);
        o.z = f2bf(T[cc4 + 2][rr]);
        o.w = f2bf(T[cc4 + 3][rr]);
        *reinterpret_cast<ushort4*>(&out[(size_t)(c0 + rr) * DD + r0 + cc4]) = o;
    }
}

// ---------------------------------------------------------------------------
// bf16 MFMA GEMM: C = A[M,K] @ Bt[N,K]^T + bias. 128x128 tile, BK=64.
// Main loop: round-16 proven form (2-barrier, 0 bank conflicts; the round-17
// counted-vmcnt pipeline was flat and added conflicts -> reverted).
// MODE 0: out fp32 [M][N], LDS-staged coalesced float4 stores.
// MODE 1: N=3072 fused QKV; fragment-packed epilogues (proven).
// ---------------------------------------------------------------------------
template <int MODE>
__global__ __launch_bounds__(256) void gemm_mfma_k(
    const __bf16* __restrict__ A, const __bf16* __restrict__ Bt,
    const float* __restrict__ bias0, const float* __restrict__ bias1,
    const float* __restrict__ bias2,
    float* __restrict__ out_f32,
    __hip_bfloat16* __restrict__ oq, __hip_bfloat16* __restrict__ ok,
    __hip_bfloat16* __restrict__ ov) {
    constexpr int K = DD;
    __shared__ char smem[32768];
    __bf16* As = (__bf16*)smem;
    __bf16* Bs = As + 128 * 64;

    const int tid  = threadIdx.x;
    const int w    = tid >> 6;
    const int lane = tid & 63;
    const int lr   = lane & 15;
    const int lg   = lane >> 4;
    const int wr   = w >> 1, wc = w & 1;
    const int bm = blockIdx.y * 128, bn = blockIdx.x * 128;

    const int srow = lane >> 3;
    const int scol = ((lane & 7) ^ srow) * 8;
    const __bf16* gA = A  + (size_t)(bm + w * 32 + srow) * K + scol;
    const __bf16* gB = Bt + (size_t)(bn + w * 32 + srow) * K + scol;
    char* ldsA = (char*)As + w * 32 * 128;
    char* ldsB = (char*)Bs + w * 32 * 128;

    f32x4 acc[4][4] = {};

    const int l7 = lr & 7;
    for (int k0 = 0; k0 < K; k0 += 64) {
#pragma unroll
        for (int c = 0; c < 4; ++c) {
            gload16(gA + (size_t)(c * 8) * K + k0, ldsA + c * 1024);
            gload16(gB + (size_t)(c * 8) * K + k0, ldsB + c * 1024);
        }
        __syncthreads();
#pragma unroll
        for (int kk = 0; kk < 2; ++kk) {
            bf16x8 a[4], b[4];
#pragma unroll
            for (int m = 0; m < 4; ++m)
                a[m] = *reinterpret_cast<const bf16x8*>(
                    As + (wr * 64 + m * 16 + lr) * 64 + (((kk * 4 + lg) ^ l7) << 3));
#pragma unroll
            for (int n = 0; n < 4; ++n)
                b[n] = *reinterpret_cast<const bf16x8*>(
                    Bs + (wc * 64 + n * 16 + lr) * 64 + (((kk * 4 + lg) ^ l7) << 3));
#pragma unroll
            for (int m = 0; m < 4; ++m)
#pragma unroll
                for (int n = 0; n < 4; ++n)
                    acc[m][n] = __builtin_amdgcn_mfma_f32_16x16x32_bf16(a[m], b[n], acc[m][n], 0, 0, 0);
        }
        __syncthreads();
    }

    if (MODE == 1) {
        const int seg = bn >> 10;                     // 0=Q,1=K,2=V (uniform/block)
        const int colbase = (bn & 1023) + wc * 64;
        const int h = colbase >> 6;
        if (seg == 2) {
            // V: direct packed ushort4 stores (proven)
#pragma unroll
            for (int n = 0; n < 4; ++n) {
                const int hd = n * 16 + lr;
                const float bv = bias2[colbase + hd];
#pragma unroll
                for (int m = 0; m < 4; ++m) {
                    const int rowb = bm + wr * 64 + m * 16 + lg * 4;
                    const int b = rowb >> 11, l0 = rowb & (LLEN - 1);
                    ushort4 st;
                    st.x = f2bf(acc[m][n][0] + bv);
                    st.y = f2bf(acc[m][n][1] + bv);
                    st.z = f2bf(acc[m][n][2] + bv);
                    st.w = f2bf(acc[m][n][3] + bv);
                    const int bh = b * NHH + h;
                    const int t  = l0 >> 5;
                    const int j  = ((hd >> 5) << 1) | ((l0 >> 4) & 1);
                    const int ln = (hd & 31) + ((l0 >> 3) & 1) * 32;
                    const int e0 = l0 & 7;
                    size_t base = ((((size_t)bh * 64 + t) * 4 + j) * 64 + ln) * 8 + e0;
                    *reinterpret_cast<ushort4*>(&ov[base]) = st;
                }
            }
        } else {
            // Q/K: RoPE -> LDS packed stage -> coalesced 16B/lane stores
            const float* biasp = (seg == 0) ? bias0 : bias1;
            const float osc = (seg == 0) ? 0.18033688011112042f : 1.0f;  // SC2 fold
            ushort* LP = (ushort*)smem + (size_t)w * 4096;  // wave-private 8KB
            __syncthreads();
#pragma unroll
            for (int n2 = 0; n2 < 2; ++n2) {
                const int d = n2 * 16 + lr;                       // 0..31
                const float tsd = exp2f((float)d * -0.4152410118609203f);
                const float bv0 = biasp[colbase + d];
                const float bv1 = biasp[colbase + d + 32];
                const int c0  = d >> 4;
                const int hi8 = (d >> 3) & 1;
#pragma unroll
                for (int m = 0; m < 4; ++m) {
#pragma unroll
                    for (int i = 0; i < 4; ++i) {
                        const int lw = m * 16 + lg * 4 + i;        // 0..63
                        const int lglob = (bm & (LLEN - 1)) + wr * 64 + lw;
                        float s, c;
                        __sincosf((float)lglob * tsd, &s, &c);
                        const float x0 = acc[m][n2][i] + bv0;
                        const float x1 = acc[m][n2 + 2][i] + bv1;
                        const int tt = lw >> 5;
                        const int ln = (lw & 31) + 32 * hi8;
                        LP[(((tt << 2) + c0) * 64 + ln) * 8 + (d & 7)] =
                            f2bf((x0 * c - x1 * s) * osc);
                        LP[(((tt << 2) + c0 + 2) * 64 + ln) * 8 + (d & 7)] =
                            f2bf((x1 * c + x0 * s) * osc);
                    }
                }
            }
            __syncthreads();
            ushort* dstp = (ushort*)((seg == 0) ? oq : ok);
            const int bh0 = (bm >> 11) * NHH + h;
            const int tg0 = ((bm & (LLEN - 1)) >> 5) + wr * 2;
#pragma unroll
            for (int tt = 0; tt < 2; ++tt)
#pragma unroll
                for (int c = 0; c < 4; ++c) {
                    us8 v = *reinterpret_cast<const us8*>(
                        &LP[(((tt << 2) + c) * 64 + lane) * 8]);
                    size_t base = ((((size_t)bh0 * 64 + tg0 + tt) * 4 + c) * 64 + lane) * 8;
                    *reinterpret_cast<us8*>(&dstp[base]) = v;
                }
        }
    } else {
        // MODE 0: two-phase LDS staging -> coalesced float4 row stores
        float* FP = (float*)smem + (size_t)w * 2048;  // 32 rows x 64 cols fp32
#pragma unroll
        for (int ph = 0; ph < 2; ++ph) {
            __syncthreads();
#pragma unroll
            for (int m2 = 0; m2 < 2; ++m2) {
                const int m = ph * 2 + m2;
#pragma unroll
                for (int n = 0; n < 4; ++n) {
                    const int col = n * 16 + lr;
                    const float bv = bias0[bn + wc * 64 + col];
#pragma unroll
                    for (int i = 0; i < 4; ++i) {
                        const int rw = m2 * 16 + lg * 4 + i;
                        FP[rw * 64 + col] = acc[m][n][i] + bv;
                    }
                }
            }
            __syncthreads();
#pragma unroll
            for (int it = 0; it < 8; ++it) {
                const int idx = it * 64 + lane;
                const int rw = idx >> 4;
                const int cq = idx & 15;
                float4 v = *reinterpret_cast<const float4*>(&FP[rw * 64 + cq * 4]);
                const int row = bm + wr * 64 + ph * 32 + rw;
                *reinterpret_cast<float4*>(
                    &out_f32[(size_t)row * DD + bn + wc * 64 + cq * 4]) = v;
            }
        }
    }
}

// ---------------------------------------------------------------------------
// Shared-KV flash attention (causal), swapped-operand 32x32 MFMA, packed Q/K/V.
// Block = (head, 4 consecutive qtiles); wave w owns qtile 4g+w and sweeps
// kv tiles t = 0..qt IN LOCKSTEP with sibling waves -> all 4 waves load the
// SAME K/V addresses per step (L1/L2 broadcast, K/V request traffic / 4).
// No split-KV => no LDS, no barriers, no merge. No-max softmax (proven);
// one shfl_xor(lsum,32) at the end; direct epilogue (round-4 proven mapping).
// Grid 512 (XCD-swizzled: 4 heads/XCD, heavy qgroups first, head-interleaved).
// ---------------------------------------------------------------------------
#define ATTN_LOAD(KF, VF, T0)                                                   \
    do {                                                                        \
        const __bf16* kp_ = kbase + (size_t)(T0) * 2048;                        \
        KF[0] = *reinterpret_cast<const bf16x8*>(kp_);                          \
        KF[1] = *reinterpret_cast<const bf16x8*>(kp_ + 512);                    \
        KF[2] = *reinterpret_cast<const bf16x8*>(kp_ + 1024);                   \
        KF[3] = *reinterpret_cast<const bf16x8*>(kp_ + 1536);                   \
        const __bf16* vp_ = vbase + (size_t)(T0) * 2048;                        \
        VF[0] = *reinterpret_cast<const bf16x8*>(vp_);                          \
        VF[1] = *reinterpret_cast<const bf16x8*>(vp_ + 512);                    \
        VF[2] = *reinterpret_cast<const bf16x8*>(vp_ + 1024);                   \
        VF[3] = *reinterpret_cast<const bf16x8*>(vp_ + 1536);                   \
    } while (0)

#define ATTN_TILE(KF, VF, T0, MASKIT, QG)                                       \
    do {                                                                        \
        f32x16 s_ = {};                                                         \
        __builtin_amdgcn_s_setprio(1);                                          \
        s_ = __builtin_amdgcn_mfma_f32_32x32x16_bf16(KF[0], qf[0], s_, 0, 0, 0);\
        s_ = __builtin_amdgcn_mfma_f32_32x32x16_bf16(KF[1], qf[1], s_, 0, 0, 0);\
        s_ = __builtin_amdgcn_mfma_f32_32x32x16_bf16(KF[2], qf[2], s_, 0, 0, 0);\
        s_ = __builtin_amdgcn_mfma_f32_32x32x16_bf16(KF[3], qf[3], s_, 0, 0, 0);\
        __builtin_amdgcn_s_setprio(0);                                          \
        float p_[16];                                                           \
        const int k0_ = (T0) * 32;                                              \
        if (MASKIT) {                                                           \
            _Pragma("unroll")                                                   \
            for (int i = 0; i < 16; ++i) {                                      \
                int kkg_ = k0_ + (i & 3) + 8 * (i >> 2) + 4 * hi;               \
                p_[i] = (kkg_ <= (QG)) ? EXP2F(s_[i]) : 0.f;                    \
            }                                                                   \
        } else {                                                                \
            _Pragma("unroll")                                                   \
            for (int i = 0; i < 16; ++i) p_[i] = EXP2F(s_[i]);                  \
        }                                                                       \
        _Pragma("unroll")                                                       \
        for (int i = 0; i < 16; ++i) lsum += p_[i];                             \
        unsigned u_[8], x_[8];                                                  \
        _Pragma("unroll")                                                       \
        for (int j = 0; j < 8; ++j)                                             \
            u_[j] = pack2(p_[2 * j], p_[2 * j + 1]);                            \
        _Pragma("unroll")                                                       \
        for (int j = 0; j < 8; ++j)                                             \
            x_[j] = (unsigned)__shfl_xor((int)u_[j], 32);                       \
        union { unsigned d[4]; bf16x8 v; } B1_, B2_;                            \
        if (hi == 0) {                                                          \
            B1_.d[0] = u_[0]; B1_.d[1] = u_[1]; B1_.d[2] = x_[0]; B1_.d[3] = x_[1]; \
            B2_.d[0] = u_[4]; B2_.d[1] = u_[5]; B2_.d[2] = x_[4]; B2_.d[3] = x_[5]; \
        } else {                                                                \
            B1_.d[0] = x_[2]; B1_.d[1] = x_[3]; B1_.d[2] = u_[2]; B1_.d[3] = u_[3]; \
            B2_.d[0] = x_[6]; B2_.d[1] = x_[7]; B2_.d[2] = u_[6]; B2_.d[3] = u_[7]; \
        }                                                                       \
        __builtin_amdgcn_s_setprio(1);                                          \
        o0 = __builtin_amdgcn_mfma_f32_32x32x16_bf16(VF[0], B1_.v, o0, 0, 0, 0);\
        o0 = __builtin_amdgcn_mfma_f32_32x32x16_bf16(VF[1], B2_.v, o0, 0, 0, 0);\
        o1 = __builtin_amdgcn_mfma_f32_32x32x16_bf16(VF[2], B1_.v, o1, 0, 0, 0);\
        o1 = __builtin_amdgcn_mfma_f32_32x32x16_bf16(VF[3], B2_.v, o1, 0, 0, 0);\
        __builtin_amdgcn_s_setprio(0);                                          \
    } while (0)

__global__ __launch_bounds__(256) void attn_mfma15_k(const __bf16* __restrict__ Qp,
                                                     const __bf16* __restrict__ Kp,
                                                     const __bf16* __restrict__ Vp,
                                                     __hip_bfloat16* __restrict__ ctx) {
    const int tid  = threadIdx.x;
    const int w    = tid >> 6;
    const int lane = tid & 63;
    const int q32  = lane & 31;
    const int hi   = lane >> 5;

    // 512 blocks: XCD = bid&7 (4 heads each); head-interleaved heavy-first
    const int bid  = blockIdx.x;
    const int bh   = (bid & 7) * 4 + ((bid >> 3) & 3);
    const int qgrp = 15 - (bid >> 5);          // heavy qgroups dispatch first
    const int qt   = qgrp * 4 + w;             // this wave's qtile (0..63)
    const int qg   = qt * 32 + q32;

    // packed Q/K/V: [bh][64 tiles][4 frags][64 lanes][8 elems]
    const __bf16* qbase = Qp + (size_t)bh * (64 * 4 * 512) + lane * 8;
    const __bf16* kbase = Kp + (size_t)bh * (64 * 4 * 512) + lane * 8;
    const __bf16* vbase = Vp + (size_t)bh * (64 * 4 * 512) + lane * 8;

    const int b = bh >> 4, h = bh & 15;

    bf16x8 qf[4];
    const __bf16* qp_ = qbase + (size_t)qt * 2048;
    qf[0] = *reinterpret_cast<const bf16x8*>(qp_);
    qf[1] = *reinterpret_cast<const bf16x8*>(qp_ + 512);
    qf[2] = *reinterpret_cast<const bf16x8*>(qp_ + 1024);
    qf[3] = *reinterpret_cast<const bf16x8*>(qp_ + 1536);

    f32x16 o0 = {}, o1 = {};
    float lsum = 0.f;

    bf16x8 kf[4], vf[4];
    for (int t = 0; t <= qt; ++t) {
        ATTN_LOAD(kf, vf, t);
        ATTN_TILE(kf, vf, t, t == qt, qg);
    }

    // epilogue: own qtile, direct write (round-4 proven mapping)
    float Lt = lsum + __shfl_xor(lsum, 32);
    const float inv = 1.0f / Lt;
    __hip_bfloat16* dst = ctx + ((size_t)(b * LLEN + qg)) * DD + h * HDD;
#pragma unroll
    for (int g = 0; g < 4; ++g) {
        ushort4 st;
        st.x = f2bf(o0[4 * g + 0] * inv);
        st.y = f2bf(o0[4 * g + 1] * inv);
        st.z = f2bf(o0[4 * g + 2] * inv);
        st.w = f2bf(o0[4 * g + 3] * inv);
        *reinterpret_cast<ushort4*>(dst + 8 * g + 4 * hi) = st;
    }
#pragma unroll
    for (int g = 0; g < 4; ++g) {
        ushort4 st;
        st.x = f2bf(o1[4 * g + 0] * inv);
        st.y = f2bf(o1[4 * g + 1] * inv);
        st.z = f2bf(o1[4 * g + 2] * inv);
        st.w = f2bf(o1[4 * g + 3] * inv);
        *reinterpret_cast<ushort4*>(dst + 32 + 8 * g + 4 * hi) = st;
    }
}

// ---------------------------------------------------------------------------
extern "C" void kernel_launch(void* const* d_in, const int* in_sizes, int n_in,
                              void* d_out, int out_size, void* d_ws, size_t ws_size,
                              hipStream_t stream) {
    const float* x    = (const float*)d_in[0];
    const float* wq_w = (const float*)d_in[1];
    const float* wq_b = (const float*)d_in[2];
    const float* wk_w = (const float*)d_in[3];
    const float* wk_b = (const float*)d_in[4];
    const float* wv_w = (const float*)d_in[5];
    const float* wv_b = (const float*)d_in[6];
    const float* wo_w = (const float*)d_in[7];
    const float* wo_b = (const float*)d_in[8];
    float* out = (float*)d_out;

    const size_t MB = 1024 * 1024;
    char* p = (char*)d_ws;
    __bf16* x16   = (__bf16*)p;            p += 8 * MB;   // [4096][1024]
    __bf16* wqkvt = (__bf16*)p;            p += 6 * MB;   // [3072][1024]
    __bf16* wot   = (__bf16*)p;            p += 2 * MB;   // [1024][1024]
    __hip_bfloat16* qp16 = (__hip_bfloat16*)p; p += 8 * MB;  // packed QP (SC2-scaled)
    __hip_bfloat16* kp16 = (__hip_bfloat16*)p; p += 8 * MB;  // packed KP
    __hip_bfloat16* vp16 = (__hip_bfloat16*)p; p += 8 * MB;  // packed VP
    __hip_bfloat16* ctx16 = (__hip_bfloat16*)p;               // [B][L][D]

    hipLaunchKernelGGL(cvt_x_k, dim3(4096), dim3(256), 0, stream, x, (ushort*)x16);
    hipLaunchKernelGGL(wt_cvt_all_k, dim3(16, 16, 4), dim3(256), 0, stream,
                       wq_w, wk_w, wv_w, wo_w, (ushort*)wqkvt, (ushort*)wot);

    // fused QKV projection + RoPE + Q scale fold + Q/K/V fragment packing
    hipLaunchKernelGGL((gemm_mfma_k<1>), dim3(24, 32), dim3(256), 0, stream,
                       x16, wqkvt, wq_b, wk_b, wv_b, (float*)nullptr, qp16, kp16, vp16);

    // attention (shared-KV lockstep waves, no LDS/barriers, no-max softmax)
    hipLaunchKernelGGL(attn_mfma15_k, dim3(512), dim3(256), 0, stream,
                       (const __bf16*)qp16, (const __bf16*)kp16, (const __bf16*)vp16, ctx16);

    // output projection (LDS-staged coalesced epilogue)
    hipLaunchKernelGGL((gemm_mfma_k<0>), dim3(8, 32), dim3(256), 0, stream,
                       (const __bf16*)ctx16, wot, wo_b, (const float*)nullptr, (const float*)nullptr,
                       out, (__hip_bfloat16*)nullptr, (__hip_bfloat16*)nullptr, (__hip_bfloat16*)nullptr);
}

// Round 19
// 110.189 us; speedup vs baseline: 1.0786x; 1.0786x over previous
//
#include <hip/hip_runtime.h>
#include <hip/hip_bf16.h>
#include <float.h>
#include <math.h>

// Problem constants: B=2, L=2048, D=1024, NH=16, HD=64
#define BB  2
#define LLEN 2048
#define DD  1024
#define NHH 16
#define HDD 64
#define MROWS (BB * LLEN)   // 4096

typedef __bf16 bf16x8  __attribute__((ext_vector_type(8)));
typedef float  f32x4   __attribute__((ext_vector_type(4)));
typedef float  f32x16  __attribute__((ext_vector_type(16)));
typedef ushort us8     __attribute__((ext_vector_type(8)));

#define EXP2F(x) __builtin_amdgcn_exp2f(x)   // 1-inst v_exp_f32

static __device__ __forceinline__ ushort f2bf(float f) {
    __hip_bfloat16 h = __float2bfloat16(f);
    return *reinterpret_cast<ushort*>(&h);
}
static __device__ __forceinline__ float bfu(ushort u) {
    unsigned x = (unsigned)u << 16;
    return __uint_as_float(x);
}
static __device__ __forceinline__ unsigned pack2(float a, float b) {
    return (unsigned)f2bf(a) | ((unsigned)f2bf(b) << 16);
}

__device__ __forceinline__ void gload16(const void* g, void* l) {
    __builtin_amdgcn_global_load_lds(
        (const __attribute__((address_space(1))) void*)g,
        (__attribute__((address_space(3))) void*)l, 16, 0, 0);
}

// ---------------------------------------------------------------------------
// x fp32 -> bf16, 4 elems/thread
// ---------------------------------------------------------------------------
__global__ __launch_bounds__(256) void cvt_x_k(const float* __restrict__ in,
                                               ushort* __restrict__ out) {
    int idx = blockIdx.x * 256 + threadIdx.x;
    float4 v = reinterpret_cast<const float4*>(in)[idx];
    ushort4 o;
    o.x = f2bf(v.x); o.y = f2bf(v.y); o.z = f2bf(v.z); o.w = f2bf(v.w);
    reinterpret_cast<ushort4*>(out)[idx] = o;
}

// ---------------------------------------------------------------------------
// All 4 weight transposes+converts in one launch: fp32 [1024][1024] -> bf16 [N][K]
// ---------------------------------------------------------------------------
__global__ __launch_bounds__(256) void wt_cvt_all_k(const float* __restrict__ w0,
                                                    const float* __restrict__ w1,
                                                    const float* __restrict__ w2,
                                                    const float* __restrict__ w3,
                                                    ushort* __restrict__ qkv,
                                                    ushort* __restrict__ wo) {
    __shared__ float T[64][65];
    const int z = blockIdx.z;
    const float* in = (z == 0) ? w0 : (z == 1) ? w1 : (z == 2) ? w2 : w3;
    ushort* out = (z < 3) ? (qkv + (size_t)z * 1024 * DD) : wo;

    const int r0 = blockIdx.y * 64, c0 = blockIdx.x * 64;
    const int tid = threadIdx.x;
    for (int i = tid; i < 64 * 16; i += 256) {
        int r = i >> 4, c4 = (i & 15) * 4;
        float4 v = *reinterpret_cast<const float4*>(&in[(size_t)(r0 + r) * DD + c0 + c4]);
        T[r][c4 + 0] = v.x; T[r][c4 + 1] = v.y; T[r][c4 + 2] = v.z; T[r][c4 + 3] = v.w;
    }
    __syncthreads();
    for (int i = tid; i < 64 * 16; i += 256) {
        int rr = i >> 4, cc4 = (i & 15) * 4;
        ushort4 o;
        o.x = f2bf(T[cc4 + 0][rr]);
        o.y = f2bf(T[cc4 + 1][rr]);
        o.z = f2bf(T[cc4 + 2][rr]);
        o.w = f2bf(T[cc4 + 3][rr]);
        *reinterpret_cast<ushort4*>(&out[(size_t)(c0 + rr) * DD + r0 + cc4]) = o;
    }
}

// ---------------------------------------------------------------------------
// bf16 MFMA GEMM: C = A[M,K] @ Bt[N,K]^T + bias. 128x128 tile, BK=64.
// Main loop: round-16 proven form. MODE 0: LDS-staged coalesced fp32 stores.
// MODE 1: N=3072 fused QKV; fragment-packed epilogues (proven).
// ---------------------------------------------------------------------------
template <int MODE>
__global__ __launch_bounds__(256) void gemm_mfma_k(
    const __bf16* __restrict__ A, const __bf16* __restrict__ Bt,
    const float* __restrict__ bias0, const float* __restrict__ bias1,
    const float* __restrict__ bias2,
    float* __restrict__ out_f32,
    __hip_bfloat16* __restrict__ oq, __hip_bfloat16* __restrict__ ok,
    __hip_bfloat16* __restrict__ ov) {
    constexpr int K = DD;
    __shared__ char smem[32768];
    __bf16* As = (__bf16*)smem;
    __bf16* Bs = As + 128 * 64;

    const int tid  = threadIdx.x;
    const int w    = tid >> 6;
    const int lane = tid & 63;
    const int lr   = lane & 15;
    const int lg   = lane >> 4;
    const int wr   = w >> 1, wc = w & 1;
    const int bm = blockIdx.y * 128, bn = blockIdx.x * 128;

    const int srow = lane >> 3;
    const int scol = ((lane & 7) ^ srow) * 8;
    const __bf16* gA = A  + (size_t)(bm + w * 32 + srow) * K + scol;
    const __bf16* gB = Bt + (size_t)(bn + w * 32 + srow) * K + scol;
    char* ldsA = (char*)As + w * 32 * 128;
    char* ldsB = (char*)Bs + w * 32 * 128;

    f32x4 acc[4][4] = {};

    const int l7 = lr & 7;
    for (int k0 = 0; k0 < K; k0 += 64) {
#pragma unroll
        for (int c = 0; c < 4; ++c) {
            gload16(gA + (size_t)(c * 8) * K + k0, ldsA + c * 1024);
            gload16(gB + (size_t)(c * 8) * K + k0, ldsB + c * 1024);
        }
        __syncthreads();
#pragma unroll
        for (int kk = 0; kk < 2; ++kk) {
            bf16x8 a[4], b[4];
#pragma unroll
            for (int m = 0; m < 4; ++m)
                a[m] = *reinterpret_cast<const bf16x8*>(
                    As + (wr * 64 + m * 16 + lr) * 64 + (((kk * 4 + lg) ^ l7) << 3));
#pragma unroll
            for (int n = 0; n < 4; ++n)
                b[n] = *reinterpret_cast<const bf16x8*>(
                    Bs + (wc * 64 + n * 16 + lr) * 64 + (((kk * 4 + lg) ^ l7) << 3));
#pragma unroll
            for (int m = 0; m < 4; ++m)
#pragma unroll
                for (int n = 0; n < 4; ++n)
                    acc[m][n] = __builtin_amdgcn_mfma_f32_16x16x32_bf16(a[m], b[n], acc[m][n], 0, 0, 0);
        }
        __syncthreads();
    }

    if (MODE == 1) {
        const int seg = bn >> 10;                     // 0=Q,1=K,2=V (uniform/block)
        const int colbase = (bn & 1023) + wc * 64;
        const int h = colbase >> 6;
        if (seg == 2) {
            // V: direct packed ushort4 stores (proven)
#pragma unroll
            for (int n = 0; n < 4; ++n) {
                const int hd = n * 16 + lr;
                const float bv = bias2[colbase + hd];
#pragma unroll
                for (int m = 0; m < 4; ++m) {
                    const int rowb = bm + wr * 64 + m * 16 + lg * 4;
                    const int b = rowb >> 11, l0 = rowb & (LLEN - 1);
                    ushort4 st;
                    st.x = f2bf(acc[m][n][0] + bv);
                    st.y = f2bf(acc[m][n][1] + bv);
                    st.z = f2bf(acc[m][n][2] + bv);
                    st.w = f2bf(acc[m][n][3] + bv);
                    const int bh = b * NHH + h;
                    const int t  = l0 >> 5;
                    const int j  = ((hd >> 5) << 1) | ((l0 >> 4) & 1);
                    const int ln = (hd & 31) + ((l0 >> 3) & 1) * 32;
                    const int e0 = l0 & 7;
                    size_t base = ((((size_t)bh * 64 + t) * 4 + j) * 64 + ln) * 8 + e0;
                    *reinterpret_cast<ushort4*>(&ov[base]) = st;
                }
            }
        } else {
            // Q/K: RoPE -> LDS packed stage -> coalesced 16B/lane stores
            const float* biasp = (seg == 0) ? bias0 : bias1;
            const float osc = (seg == 0) ? 0.18033688011112042f : 1.0f;  // SC2 fold
            ushort* LP = (ushort*)smem + (size_t)w * 4096;  // wave-private 8KB
            __syncthreads();
#pragma unroll
            for (int n2 = 0; n2 < 2; ++n2) {
                const int d = n2 * 16 + lr;                       // 0..31
                const float tsd = exp2f((float)d * -0.4152410118609203f);
                const float bv0 = biasp[colbase + d];
                const float bv1 = biasp[colbase + d + 32];
                const int c0  = d >> 4;
                const int hi8 = (d >> 3) & 1;
#pragma unroll
                for (int m = 0; m < 4; ++m) {
#pragma unroll
                    for (int i = 0; i < 4; ++i) {
                        const int lw = m * 16 + lg * 4 + i;        // 0..63
                        const int lglob = (bm & (LLEN - 1)) + wr * 64 + lw;
                        float s, c;
                        __sincosf((float)lglob * tsd, &s, &c);
                        const float x0 = acc[m][n2][i] + bv0;
                        const float x1 = acc[m][n2 + 2][i] + bv1;
                        const int tt = lw >> 5;
                        const int ln = (lw & 31) + 32 * hi8;
                        LP[(((tt << 2) + c0) * 64 + ln) * 8 + (d & 7)] =
                            f2bf((x0 * c - x1 * s) * osc);
                        LP[(((tt << 2) + c0 + 2) * 64 + ln) * 8 + (d & 7)] =
                            f2bf((x1 * c + x0 * s) * osc);
                    }
                }
            }
            __syncthreads();
            ushort* dstp = (ushort*)((seg == 0) ? oq : ok);
            const int bh0 = (bm >> 11) * NHH + h;
            const int tg0 = ((bm & (LLEN - 1)) >> 5) + wr * 2;
#pragma unroll
            for (int tt = 0; tt < 2; ++tt)
#pragma unroll
                for (int c = 0; c < 4; ++c) {
                    us8 v = *reinterpret_cast<const us8*>(
                        &LP[(((tt << 2) + c) * 64 + lane) * 8]);
                    size_t base = ((((size_t)bh0 * 64 + tg0 + tt) * 4 + c) * 64 + lane) * 8;
                    *reinterpret_cast<us8*>(&dstp[base]) = v;
                }
        }
    } else {
        // MODE 0: two-phase LDS staging -> coalesced float4 row stores
        float* FP = (float*)smem + (size_t)w * 2048;  // 32 rows x 64 cols fp32
#pragma unroll
        for (int ph = 0; ph < 2; ++ph) {
            __syncthreads();
#pragma unroll
            for (int m2 = 0; m2 < 2; ++m2) {
                const int m = ph * 2 + m2;
#pragma unroll
                for (int n = 0; n < 4; ++n) {
                    const int col = n * 16 + lr;
                    const float bv = bias0[bn + wc * 64 + col];
#pragma unroll
                    for (int i = 0; i < 4; ++i) {
                        const int rw = m2 * 16 + lg * 4 + i;
                        FP[rw * 64 + col] = acc[m][n][i] + bv;
                    }
                }
            }
            __syncthreads();
#pragma unroll
            for (int it = 0; it < 8; ++it) {
                const int idx = it * 64 + lane;
                const int rw = idx >> 4;
                const int cq = idx & 15;
                float4 v = *reinterpret_cast<const float4*>(&FP[rw * 64 + cq * 4]);
                const int row = bm + wr * 64 + ph * 32 + rw;
                *reinterpret_cast<float4*>(
                    &out_f32[(size_t)row * DD + bn + wc * 64 + cq * 4]) = v;
            }
        }
    }
}

// ---------------------------------------------------------------------------
// Paired-qtile flash attention (causal), swapped-operand 32x32 MFMA.
// Round-16 structure (best: 109.9us total) with ONE change: O-partials in
// LDS are bf16 (pack2/bfu, proven rounds 9-12) -> LDS 35.8KB -> 18.4KB ->
// 4 -> 6 blocks/CU (VGPR 76 allows 6). More resident waves hide the
// remaining latency (attn was ~55% VALU-busy, rest latency).
// ---------------------------------------------------------------------------
#define ATTN_LOAD(KF, VF, T0)                                                   \
    do {                                                                        \
        const __bf16* kp_ = kbase + (size_t)(T0) * 2048;                        \
        KF[0] = *reinterpret_cast<const bf16x8*>(kp_);                          \
        KF[1] = *reinterpret_cast<const bf16x8*>(kp_ + 512);                    \
        KF[2] = *reinterpret_cast<const bf16x8*>(kp_ + 1024);                   \
        KF[3] = *reinterpret_cast<const bf16x8*>(kp_ + 1536);                   \
        const __bf16* vp_ = vbase + (size_t)(T0) * 2048;                        \
        VF[0] = *reinterpret_cast<const bf16x8*>(vp_);                          \
        VF[1] = *reinterpret_cast<const bf16x8*>(vp_ + 512);                    \
        VF[2] = *reinterpret_cast<const bf16x8*>(vp_ + 1024);                   \
        VF[3] = *reinterpret_cast<const bf16x8*>(vp_ + 1536);                   \
    } while (0)

#define ATTN_TILE(KF, VF, T0, MASKIT, QG)                                       \
    do {                                                                        \
        f32x16 s_ = {};                                                         \
        __builtin_amdgcn_s_setprio(1);                                          \
        s_ = __builtin_amdgcn_mfma_f32_32x32x16_bf16(KF[0], qf[0], s_, 0, 0, 0);\
        s_ = __builtin_amdgcn_mfma_f32_32x32x16_bf16(KF[1], qf[1], s_, 0, 0, 0);\
        s_ = __builtin_amdgcn_mfma_f32_32x32x16_bf16(KF[2], qf[2], s_, 0, 0, 0);\
        s_ = __builtin_amdgcn_mfma_f32_32x32x16_bf16(KF[3], qf[3], s_, 0, 0, 0);\
        __builtin_amdgcn_s_setprio(0);                                          \
        float p_[16];                                                           \
        const int k0_ = (T0) * 32;                                              \
        if (MASKIT) {                                                           \
            _Pragma("unroll")                                                   \
            for (int i = 0; i < 16; ++i) {                                      \
                int kkg_ = k0_ + (i & 3) + 8 * (i >> 2) + 4 * hi;               \
                p_[i] = (kkg_ <= (QG)) ? EXP2F(s_[i]) : 0.f;                    \
            }                                                                   \
        } else {                                                                \
            _Pragma("unroll")                                                   \
            for (int i = 0; i < 16; ++i) p_[i] = EXP2F(s_[i]);                  \
        }                                                                       \
        _Pragma("unroll")                                                       \
        for (int i = 0; i < 16; ++i) lsum += p_[i];                             \
        unsigned u_[8], x_[8];                                                  \
        _Pragma("unroll")                                                       \
        for (int j = 0; j < 8; ++j)                                             \
            u_[j] = pack2(p_[2 * j], p_[2 * j + 1]);                            \
        _Pragma("unroll")                                                       \
        for (int j = 0; j < 8; ++j)                                             \
            x_[j] = (unsigned)__shfl_xor((int)u_[j], 32);                       \
        union { unsigned d[4]; bf16x8 v; } B1_, B2_;                            \
        if (hi == 0) {                                                          \
            B1_.d[0] = u_[0]; B1_.d[1] = u_[1]; B1_.d[2] = x_[0]; B1_.d[3] = x_[1]; \
            B2_.d[0] = u_[4]; B2_.d[1] = u_[5]; B2_.d[2] = x_[4]; B2_.d[3] = x_[5]; \
        } else {                                                                \
            B1_.d[0] = x_[2]; B1_.d[1] = x_[3]; B1_.d[2] = u_[2]; B1_.d[3] = u_[3]; \
            B2_.d[0] = x_[6]; B2_.d[1] = x_[7]; B2_.d[2] = u_[6]; B2_.d[3] = u_[7]; \
        }                                                                       \
        __builtin_amdgcn_s_setprio(1);                                          \
        o0 = __builtin_amdgcn_mfma_f32_32x32x16_bf16(VF[0], B1_.v, o0, 0, 0, 0);\
        o0 = __builtin_amdgcn_mfma_f32_32x32x16_bf16(VF[1], B2_.v, o0, 0, 0, 0);\
        o1 = __builtin_amdgcn_mfma_f32_32x32x16_bf16(VF[2], B1_.v, o1, 0, 0, 0);\
        o1 = __builtin_amdgcn_mfma_f32_32x32x16_bf16(VF[3], B2_.v, o1, 0, 0, 0);\
        __builtin_amdgcn_s_setprio(0);                                          \
    } while (0)

#define ATTN_COMPUTE(QT, QG)                                                    \
    do {                                                                        \
        lsum = 0.f;                                                             \
        o0 = (f32x16){}; o1 = (f32x16){};                                       \
        const __bf16* qp_ = qbase + (size_t)(QT) * 2048;                        \
        qf[0] = *reinterpret_cast<const bf16x8*>(qp_);                          \
        qf[1] = *reinterpret_cast<const bf16x8*>(qp_ + 512);                    \
        qf[2] = *reinterpret_cast<const bf16x8*>(qp_ + 1024);                   \
        qf[3] = *reinterpret_cast<const bf16x8*>(qp_ + 1536);                   \
        bf16x8 kf[4], vf[4];                                                    \
        for (int t = w; t <= (QT); t += 4) {                                    \
            ATTN_LOAD(kf, vf, t);                                               \
            ATTN_TILE(kf, vf, t, t == (QT), QG);                                \
        }                                                                       \
    } while (0)

#define ATTN_WRITE_PARTIALS()                                                   \
    do {                                                                        \
        _Pragma("unroll")                                                       \
        for (int r = 0; r < 16; r += 2) {                                       \
            *reinterpret_cast<unsigned*>(&oLs[w][lane][r])      = pack2(o0[r], o0[r + 1]); \
            *reinterpret_cast<unsigned*>(&oLs[w][lane][16 + r]) = pack2(o1[r], o1[r + 1]); \
        }                                                                       \
        lvL[w][lane] = lsum;                                                    \
    } while (0)

#define ATTN_MERGE_WRITE(QG)                                                    \
    do {                                                                        \
        float Lt = 0.f;                                                         \
        _Pragma("unroll")                                                       \
        for (int j = 0; j < 4; ++j)                                             \
            Lt += lvL[j][q32] + lvL[j][q32 + 32];                               \
        const float inv = 1.0f / Lt;                                            \
        __hip_bfloat16* dst = ctx + ((size_t)(b * LLEN + (QG))) * DD + h * HDD; \
        const int T = w >> 1;                                                   \
        const int gb = (w & 1) * 2;                                             \
        _Pragma("unroll")                                                       \
        for (int g2 = 0; g2 < 2; ++g2) {                                        \
            const int g = gb + g2;                                              \
            const int rb = T * 16 + 4 * g;                                      \
            float acc4[4] = {0.f, 0.f, 0.f, 0.f};                               \
            _Pragma("unroll")                                                   \
            for (int j = 0; j < 4; ++j) {                                       \
                unsigned a = *reinterpret_cast<const unsigned*>(&oLs[j][lane][rb]);     \
                unsigned c = *reinterpret_cast<const unsigned*>(&oLs[j][lane][rb + 2]); \
                acc4[0] += bfu((ushort)(a & 0xffff));                           \
                acc4[1] += bfu((ushort)(a >> 16));                              \
                acc4[2] += bfu((ushort)(c & 0xffff));                           \
                acc4[3] += bfu((ushort)(c >> 16));                              \
            }                                                                   \
            ushort st4[4];                                                      \
            _Pragma("unroll")                                                   \
            for (int e = 0; e < 4; ++e) st4[e] = f2bf(acc4[e] * inv);           \
            const int d = T * 32 + 8 * g + 4 * hi;                              \
            *reinterpret_cast<ushort4*>(dst + d) =                              \
                *reinterpret_cast<ushort4*>(st4);                               \
        }                                                                       \
    } while (0)

__global__ __launch_bounds__(256) void attn_mfma16_k(const __bf16* __restrict__ Qp,
                                                     const __bf16* __restrict__ Kp,
                                                     const __bf16* __restrict__ Vp,
                                                     __hip_bfloat16* __restrict__ ctx) {
    __shared__ ushort oLs[4][64][34];   // bf16 partials; stride 34 -> 2-way (free)
    __shared__ float lvL[4][64];

    const int tid  = threadIdx.x;
    const int w    = tid >> 6;
    const int lane = tid & 63;
    const int q32  = lane & 31;
    const int hi   = lane >> 5;

    // XCD swizzle: 1024 blocks -> 128-chunk per XCD (4 heads per XCD)
    const int bid = blockIdx.x;
    const int g_  = (bid & 7) * 128 + (bid >> 3);
    const int bh  = g_ >> 5;          // 0..31
    const int ap  = g_ & 31;          // pair index
    const int qtA = 63 - ap;          // heavy qtile
    const int qtB = ap;               // light qtile
    const int qgA = qtA * 32 + q32;
    const int qgB = qtB * 32 + q32;

    // packed Q/K/V: [bh][64 tiles][4 frags][64 lanes][8 elems]
    const __bf16* qbase = Qp + (size_t)bh * (64 * 4 * 512) + lane * 8;
    const __bf16* kbase = Kp + (size_t)bh * (64 * 4 * 512) + lane * 8;
    const __bf16* vbase = Vp + (size_t)bh * (64 * 4 * 512) + lane * 8;

    const int b = bh >> 4, h = bh & 15;

    bf16x8 qf[4];
    f32x16 o0, o1;
    float lsum;

    // ---- phase A (heavy qtile) ----
    ATTN_COMPUTE(qtA, qgA);
    ATTN_WRITE_PARTIALS();
    __syncthreads();
    ATTN_MERGE_WRITE(qgA);

    // ---- phase B compute overlaps other waves' merge-A reads ----
    ATTN_COMPUTE(qtB, qgB);
    __syncthreads();   // all merge-A LDS reads complete
    ATTN_WRITE_PARTIALS();
    __syncthreads();
    ATTN_MERGE_WRITE(qgB);
}

// ---------------------------------------------------------------------------
extern "C" void kernel_launch(void* const* d_in, const int* in_sizes, int n_in,
                              void* d_out, int out_size, void* d_ws, size_t ws_size,
                              hipStream_t stream) {
    const float* x    = (const float*)d_in[0];
    const float* wq_w = (const float*)d_in[1];
    const float* wq_b = (const float*)d_in[2];
    const float* wk_w = (const float*)d_in[3];
    const float* wk_b = (const float*)d_in[4];
    const float* wv_w = (const float*)d_in[5];
    const float* wv_b = (const float*)d_in[6];
    const float* wo_w = (const float*)d_in[7];
    const float* wo_b = (const float*)d_in[8];
    float* out = (float*)d_out;

    const size_t MB = 1024 * 1024;
    char* p = (char*)d_ws;
    __bf16* x16   = (__bf16*)p;            p += 8 * MB;   // [4096][1024]
    __bf16* wqkvt = (__bf16*)p;            p += 6 * MB;   // [3072][1024]
    __bf16* wot   = (__bf16*)p;            p += 2 * MB;   // [1024][1024]
    __hip_bfloat16* qp16 = (__hip_bfloat16*)p; p += 8 * MB;  // packed QP (SC2-scaled)
    __hip_bfloat16* kp16 = (__hip_bfloat16*)p; p += 8 * MB;  // packed KP
    __hip_bfloat16* vp16 = (__hip_bfloat16*)p; p += 8 * MB;  // packed VP
    __hip_bfloat16* ctx16 = (__hip_bfloat16*)p;               // [B][L][D]

    hipLaunchKernelGGL(cvt_x_k, dim3(4096), dim3(256), 0, stream, x, (ushort*)x16);
    hipLaunchKernelGGL(wt_cvt_all_k, dim3(16, 16, 4), dim3(256), 0, stream,
                       wq_w, wk_w, wv_w, wo_w, (ushort*)wqkvt, (ushort*)wot);

    // fused QKV projection + RoPE + Q scale fold + Q/K/V fragment packing
    hipLaunchKernelGGL((gemm_mfma_k<1>), dim3(24, 32), dim3(256), 0, stream,
                       x16, wqkvt, wq_b, wk_b, wv_b, (float*)nullptr, qp16, kp16, vp16);

    // attention (paired-qtile, packed Q/K/V, no-max softmax, bf16 partials)
    hipLaunchKernelGGL(attn_mfma16_k, dim3(1024), dim3(256), 0, stream,
                       (const __bf16*)qp16, (const __bf16*)kp16, (const __bf16*)vp16, ctx16);

    // output projection (LDS-staged coalesced epilogue)
    hipLaunchKernelGGL((gemm_mfma_k<0>), dim3(8, 32), dim3(256), 0, stream,
                       (const __bf16*)ctx16, wot, wo_b, (const float*)nullptr, (const float*)nullptr,
                       out, (__hip_bfloat16*)nullptr, (__hip_bfloat16*)nullptr, (__hip_bfloat16*)nullptr);
}

// Round 20
// 103.880 us; speedup vs baseline: 1.1442x; 1.0607x over previous
//
#include <hip/hip_runtime.h>
#include <hip/hip_bf16.h>
#include <float.h>
#include <math.h>

// Problem constants: B=2, L=2048, D=1024, NH=16, HD=64
#define BB  2
#define LLEN 2048
#define DD  1024
#define NHH 16
#define HDD 64
#define MROWS (BB * LLEN)   // 4096

typedef __bf16 bf16x8  __attribute__((ext_vector_type(8)));
typedef float  f32x4   __attribute__((ext_vector_type(4)));
typedef float  f32x16  __attribute__((ext_vector_type(16)));
typedef ushort us8     __attribute__((ext_vector_type(8)));

#define EXP2F(x) __builtin_amdgcn_exp2f(x)   // 1-inst v_exp_f32

static __device__ __forceinline__ ushort f2bf(float f) {
    __hip_bfloat16 h = __float2bfloat16(f);
    return *reinterpret_cast<ushort*>(&h);
}
static __device__ __forceinline__ float bfu(ushort u) {
    unsigned x = (unsigned)u << 16;
    return __uint_as_float(x);
}
static __device__ __forceinline__ unsigned pack2(float a, float b) {
    return (unsigned)f2bf(a) | ((unsigned)f2bf(b) << 16);
}

__device__ __forceinline__ void gload16(const void* g, void* l) {
    __builtin_amdgcn_global_load_lds(
        (const __attribute__((address_space(1))) void*)g,
        (__attribute__((address_space(3))) void*)l, 16, 0, 0);
}

// ---------------------------------------------------------------------------
// x fp32 -> bf16, 4 elems/thread
// ---------------------------------------------------------------------------
__global__ __launch_bounds__(256) void cvt_x_k(const float* __restrict__ in,
                                               ushort* __restrict__ out) {
    int idx = blockIdx.x * 256 + threadIdx.x;
    float4 v = reinterpret_cast<const float4*>(in)[idx];
    ushort4 o;
    o.x = f2bf(v.x); o.y = f2bf(v.y); o.z = f2bf(v.z); o.w = f2bf(v.w);
    reinterpret_cast<ushort4*>(out)[idx] = o;
}

// ---------------------------------------------------------------------------
// All 4 weight transposes+converts in one launch: fp32 [1024][1024] -> bf16 [N][K]
// ---------------------------------------------------------------------------
__global__ __launch_bounds__(256) void wt_cvt_all_k(const float* __restrict__ w0,
                                                    const float* __restrict__ w1,
                                                    const float* __restrict__ w2,
                                                    const float* __restrict__ w3,
                                                    ushort* __restrict__ qkv,
                                                    ushort* __restrict__ wo) {
    __shared__ float T[64][65];
    const int z = blockIdx.z;
    const float* in = (z == 0) ? w0 : (z == 1) ? w1 : (z == 2) ? w2 : w3;
    ushort* out = (z < 3) ? (qkv + (size_t)z * 1024 * DD) : wo;

    const int r0 = blockIdx.y * 64, c0 = blockIdx.x * 64;
    const int tid = threadIdx.x;
    for (int i = tid; i < 64 * 16; i += 256) {
        int r = i >> 4, c4 = (i & 15) * 4;
        float4 v = *reinterpret_cast<const float4*>(&in[(size_t)(r0 + r) * DD + c0 + c4]);
        T[r][c4 + 0] = v.x; T[r][c4 + 1] = v.y; T[r][c4 + 2] = v.z; T[r][c4 + 3] = v.w;
    }
    __syncthreads();
    for (int i = tid; i < 64 * 16; i += 256) {
        int rr = i >> 4, cc4 = (i & 15) * 4;
        ushort4 o;
        o.x = f2bf(T[cc4 + 0][rr]);
        o.y = f2bf(T[cc4 + 1][rr]);
        o.z = f2bf(T[cc4 + 2][rr]);
        o.w = f2bf(T[cc4 + 3][rr]);
        *reinterpret_cast<ushort4*>(&out[(size_t)(c0 + rr) * DD + r0 + cc4]) = o;
    }
}

// ---------------------------------------------------------------------------
// bf16 MFMA GEMM: C = A[M,K] @ Bt[N,K]^T + bias. SMALL-TILE re-tiling:
//   MODE 1 (QKV): tile 64x128, grid (24,64) = 1536 blocks = 6/CU, LDS 24KB.
//   MODE 0 (out): tile 64x64,  grid (16,64) = 1024 blocks = 4/CU, LDS 16KB.
// Rationale: round-16/17/19 showed the 128^2 form capped at MfmaUtil ~22%
// because only 3 (QKV) / 1 (out) barrier-groups per CU exist to cover each
// other's vmcnt(0) drains. Smaller tiles = more concurrent blocks/CU.
// 4 waves, each 16 rows x full tile width; NF n-frags (8 or 4), acc = NF x f32x4.
// Staging/read XOR swizzle identical in form to the proven 128^2 kernel.
// Epilogues re-derived for 16-row waves (packed QP/KP/VP formulas preserved).
// ---------------------------------------------------------------------------
template <int MODE>
__global__ __launch_bounds__(256, 6) void gemm_mfma_k(
    const __bf16* __restrict__ A, const __bf16* __restrict__ Bt,
    const float* __restrict__ bias0, const float* __restrict__ bias1,
    const float* __restrict__ bias2,
    float* __restrict__ out_f32,
    __hip_bfloat16* __restrict__ oq, __hip_bfloat16* __restrict__ ok,
    __hip_bfloat16* __restrict__ ov) {
    constexpr int K  = DD;
    constexpr int NF = (MODE == 1) ? 8 : 4;      // n-frags per wave
    constexpr int BN = NF * 16;                  // tile N: 128 or 64
    constexpr int SMEMB = (64 + BN) * 64 * 2;    // 24576 or 16384
    __shared__ char smem[SMEMB];
    __bf16* As = (__bf16*)smem;                  // [64][64]
    __bf16* Bs = As + 64 * 64;                   // [BN][64]

    const int tid  = threadIdx.x;
    const int w    = tid >> 6;
    const int lane = tid & 63;
    const int lr   = lane & 15;
    const int lg   = lane >> 4;
    const int bm = blockIdx.y * 64, bn = blockIdx.x * BN;

    const int srow8 = lane >> 3;                 // 0..7
    const int schk  = (lane & 7) ^ srow8;        // pre-swizzled src chunk
    const __bf16* gA = A  + (size_t)(bm + w * 16 + srow8) * K + schk * 8;
    const __bf16* gB = Bt + (size_t)(bn + w * (NF * 4) + srow8) * K + schk * 8;
    char* ldsA = (char*)As + w * 16 * 128;       // bytes (row = 128B)
    char* ldsB = (char*)Bs + w * (NF * 4) * 128;

    f32x4 acc[NF] = {};
    const int l7 = lr & 7;

    for (int k0 = 0; k0 < K; k0 += 64) {
#pragma unroll
        for (int c = 0; c < 2; ++c)
            gload16(gA + (size_t)(c * 8) * K + k0, ldsA + c * 1024);
#pragma unroll
        for (int c = 0; c < NF / 2; ++c)
            gload16(gB + (size_t)(c * 8) * K + k0, ldsB + c * 1024);
        __syncthreads();
#pragma unroll
        for (int kk = 0; kk < 2; ++kk) {
            const int rchk = ((kk * 4 + lg) ^ l7) << 3;
            bf16x8 a = *reinterpret_cast<const bf16x8*>(As + (w * 16 + lr) * 64 + rchk);
#pragma unroll
            for (int n = 0; n < NF; ++n) {
                bf16x8 b = *reinterpret_cast<const bf16x8*>(Bs + (n * 16 + lr) * 64 + rchk);
                acc[n] = __builtin_amdgcn_mfma_f32_16x16x32_bf16(a, b, acc[n], 0, 0, 0);
            }
        }
        __syncthreads();
    }

    if (MODE == 1) {
        const int seg = bn >> 10;                     // 0=Q,1=K,2=V (uniform/block)
        const int colbase = bn & 1023;                // 128-col base (2 heads)
        const int h0 = colbase >> 6;
        const int b  = bm >> 11;
        const int bmL = bm & 2047;
        if (seg == 2) {
            // V: direct packed ushort4 stores (formula proven rounds 14-19)
#pragma unroll
            for (int n = 0; n < NF; ++n) {
                const int h  = h0 + (n >> 2);
                const int hd = (n & 3) * 16 + lr;
                const float bv = bias2[colbase + n * 16 + lr];
                const int rowb = bm + w * 16 + lg * 4;
                const int l0 = rowb & 2047;
                ushort4 st;
                st.x = f2bf(acc[n][0] + bv);
                st.y = f2bf(acc[n][1] + bv);
                st.z = f2bf(acc[n][2] + bv);
                st.w = f2bf(acc[n][3] + bv);
                const int bh = b * NHH + h;
                const int t  = l0 >> 5;
                const int j  = ((hd >> 5) << 1) | ((l0 >> 4) & 1);
                const int ln = (hd & 31) + ((l0 >> 3) & 1) * 32;
                const int e0 = l0 & 7;
                size_t base = ((((size_t)bh * 64 + t) * 4 + j) * 64 + ln) * 8 + e0;
                *reinterpret_cast<ushort4*>(&ov[base]) = st;
            }
        } else {
            // Q/K: RoPE -> LDS packed stage (4KB/wave) -> coalesced us8 stores
            const float* biasp = (seg == 0) ? bias0 : bias1;
            const float osc = (seg == 0) ? 0.18033688011112042f : 1.0f;  // SC2 fold
            ushort* LP = (ushort*)smem + w * 2048;     // 2048 shorts = 4KB
#pragma unroll
            for (int hh = 0; hh < 2; ++hh) {
#pragma unroll
                for (int n2 = 0; n2 < 2; ++n2) {
                    const int nA = hh * 4 + n2, nB = nA + 2;
                    const int d  = n2 * 16 + lr;                 // 0..31
                    const float tsd = exp2f((float)d * -0.4152410118609203f);
                    const float bv0 = biasp[colbase + hh * 64 + d];
                    const float bv1 = biasp[colbase + hh * 64 + d + 32];
                    const int c0  = d >> 4;
                    const int hi8 = (d >> 3) & 1;
#pragma unroll
                    for (int i = 0; i < 4; ++i) {
                        const int lw = lg * 4 + i;               // 0..15
                        const int l  = bmL + w * 16 + lw;
                        float s, c;
                        __sincosf((float)l * tsd, &s, &c);
                        const float x0 = acc[nA][i] + bv0;
                        const float x1 = acc[nB][i] + bv1;
                        const int lnL = lw + 16 * hi8;           // 0..31
                        LP[hh * 1024 + (c0 * 32 + lnL) * 8 + (d & 7)] =
                            f2bf((x0 * c - x1 * s) * osc);
                        LP[hh * 1024 + ((c0 + 2) * 32 + lnL) * 8 + (d & 7)] =
                            f2bf((x1 * c + x0 * s) * osc);
                    }
                }
            }
            __syncthreads();
            ushort* dstp = (ushort*)((seg == 0) ? oq : ok);
            const int t   = (bmL >> 5) + (w >> 1);
            const int r0w = (w & 1) * 16;
#pragma unroll
            for (int hh = 0; hh < 2; ++hh) {
                const int bh = b * NHH + h0 + hh;
#pragma unroll
                for (int it = 0; it < 2; ++it) {
                    const int f = it * 64 + lane;                // 0..127
                    const int c = f >> 5, lnL = f & 31;
                    const int ln = r0w + (lnL & 15) + 32 * (lnL >> 4);
                    us8 v = *reinterpret_cast<const us8*>(&LP[hh * 1024 + f * 8]);
                    size_t base = ((((size_t)bh * 64 + t) * 4 + c) * 64 + ln) * 8;
                    *reinterpret_cast<us8*>(&dstp[base]) = v;
                }
            }
        }
    } else {
        // MODE 0: LDS-staged coalesced float4 row stores (4KB/wave)
        float* FP = (float*)smem + w * 1024;   // 16 rows x 64 cols fp32
        __syncthreads();
#pragma unroll
        for (int n = 0; n < NF; ++n) {
            const int col = n * 16 + lr;
            const float bv = bias0[bn + col];
#pragma unroll
            for (int i = 0; i < 4; ++i)
                FP[(lg * 4 + i) * 64 + col] = acc[n][i] + bv;
        }
        __syncthreads();
#pragma unroll
        for (int it = 0; it < 4; ++it) {
            const int f = it * 64 + lane;          // 0..255
            const int row16 = f >> 4, cq = f & 15;
            float4 v = *reinterpret_cast<const float4*>(&FP[row16 * 64 + cq * 4]);
            const int row = bm + w * 16 + row16;
            *reinterpret_cast<float4*>(&out_f32[(size_t)row * DD + bn + cq * 4]) = v;
        }
    }
}

// ---------------------------------------------------------------------------
// Paired-qtile flash attention (causal), swapped-operand 32x32 MFMA.
// Packed Q/K/V, no-max softmax, bf16 LDS partials. (round-19, passing)
// ---------------------------------------------------------------------------
#define ATTN_LOAD(KF, VF, T0)                                                   \
    do {                                                                        \
        const __bf16* kp_ = kbase + (size_t)(T0) * 2048;                        \
        KF[0] = *reinterpret_cast<const bf16x8*>(kp_);                          \
        KF[1] = *reinterpret_cast<const bf16x8*>(kp_ + 512);                    \
        KF[2] = *reinterpret_cast<const bf16x8*>(kp_ + 1024);                   \
        KF[3] = *reinterpret_cast<const bf16x8*>(kp_ + 1536);                   \
        const __bf16* vp_ = vbase + (size_t)(T0) * 2048;                        \
        VF[0] = *reinterpret_cast<const bf16x8*>(vp_);                          \
        VF[1] = *reinterpret_cast<const bf16x8*>(vp_ + 512);                    \
        VF[2] = *reinterpret_cast<const bf16x8*>(vp_ + 1024);                   \
        VF[3] = *reinterpret_cast<const bf16x8*>(vp_ + 1536);                   \
    } while (0)

#define ATTN_TILE(KF, VF, T0, MASKIT, QG)                                       \
    do {                                                                        \
        f32x16 s_ = {};                                                         \
        __builtin_amdgcn_s_setprio(1);                                          \
        s_ = __builtin_amdgcn_mfma_f32_32x32x16_bf16(KF[0], qf[0], s_, 0, 0, 0);\
        s_ = __builtin_amdgcn_mfma_f32_32x32x16_bf16(KF[1], qf[1], s_, 0, 0, 0);\
        s_ = __builtin_amdgcn_mfma_f32_32x32x16_bf16(KF[2], qf[2], s_, 0, 0, 0);\
        s_ = __builtin_amdgcn_mfma_f32_32x32x16_bf16(KF[3], qf[3], s_, 0, 0, 0);\
        __builtin_amdgcn_s_setprio(0);                                          \
        float p_[16];                                                           \
        const int k0_ = (T0) * 32;                                              \
        if (MASKIT) {                                                           \
            _Pragma("unroll")                                                   \
            for (int i = 0; i < 16; ++i) {                                      \
                int kkg_ = k0_ + (i & 3) + 8 * (i >> 2) + 4 * hi;               \
                p_[i] = (kkg_ <= (QG)) ? EXP2F(s_[i]) : 0.f;                    \
            }                                                                   \
        } else {                                                                \
            _Pragma("unroll")                                                   \
            for (int i = 0; i < 16; ++i) p_[i] = EXP2F(s_[i]);                  \
        }                                                                       \
        _Pragma("unroll")                                                       \
        for (int i = 0; i < 16; ++i) lsum += p_[i];                             \
        unsigned u_[8], x_[8];                                                  \
        _Pragma("unroll")                                                       \
        for (int j = 0; j < 8; ++j)                                             \
            u_[j] = pack2(p_[2 * j], p_[2 * j + 1]);                            \
        _Pragma("unroll")                                                       \
        for (int j = 0; j < 8; ++j)                                             \
            x_[j] = (unsigned)__shfl_xor((int)u_[j], 32);                       \
        union { unsigned d[4]; bf16x8 v; } B1_, B2_;                            \
        if (hi == 0) {                                                          \
            B1_.d[0] = u_[0]; B1_.d[1] = u_[1]; B1_.d[2] = x_[0]; B1_.d[3] = x_[1]; \
            B2_.d[0] = u_[4]; B2_.d[1] = u_[5]; B2_.d[2] = x_[4]; B2_.d[3] = x_[5]; \
        } else {                                                                \
            B1_.d[0] = x_[2]; B1_.d[1] = x_[3]; B1_.d[2] = u_[2]; B1_.d[3] = u_[3]; \
            B2_.d[0] = x_[6]; B2_.d[1] = x_[7]; B2_.d[2] = u_[6]; B2_.d[3] = u_[7]; \
        }                                                                       \
        __builtin_amdgcn_s_setprio(1);                                          \
        o0 = __builtin_amdgcn_mfma_f32_32x32x16_bf16(VF[0], B1_.v, o0, 0, 0, 0);\
        o0 = __builtin_amdgcn_mfma_f32_32x32x16_bf16(VF[1], B2_.v, o0, 0, 0, 0);\
        o1 = __builtin_amdgcn_mfma_f32_32x32x16_bf16(VF[2], B1_.v, o1, 0, 0, 0);\
        o1 = __builtin_amdgcn_mfma_f32_32x32x16_bf16(VF[3], B2_.v, o1, 0, 0, 0);\
        __builtin_amdgcn_s_setprio(0);                                          \
    } while (0)

#define ATTN_COMPUTE(QT, QG)                                                    \
    do {                                                                        \
        lsum = 0.f;                                                             \
        o0 = (f32x16){}; o1 = (f32x16){};                                       \
        const __bf16* qp_ = qbase + (size_t)(QT) * 2048;                        \
        qf[0] = *reinterpret_cast<const bf16x8*>(qp_);                          \
        qf[1] = *reinterpret_cast<const bf16x8*>(qp_ + 512);                    \
        qf[2] = *reinterpret_cast<const bf16x8*>(qp_ + 1024);                   \
        qf[3] = *reinterpret_cast<const bf16x8*>(qp_ + 1536);                   \
        bf16x8 kf[4], vf[4];                                                    \
        for (int t = w; t <= (QT); t += 4) {                                    \
            ATTN_LOAD(kf, vf, t);                                               \
            ATTN_TILE(kf, vf, t, t == (QT), QG);                                \
        }                                                                       \
    } while (0)

#define ATTN_WRITE_PARTIALS()                                                   \
    do {                                                                        \
        _Pragma("unroll")                                                       \
        for (int r = 0; r < 16; r += 2) {                                       \
            *reinterpret_cast<unsigned*>(&oLs[w][lane][r])      = pack2(o0[r], o0[r + 1]); \
            *reinterpret_cast<unsigned*>(&oLs[w][lane][16 + r]) = pack2(o1[r], o1[r + 1]); \
        }                                                                       \
        lvL[w][lane] = lsum;                                                    \
    } while (0)

#define ATTN_MERGE_WRITE(QG)                                                    \
    do {                                                                        \
        float Lt = 0.f;                                                         \
        _Pragma("unroll")                                                       \
        for (int j = 0; j < 4; ++j)                                             \
            Lt += lvL[j][q32] + lvL[j][q32 + 32];                               \
        const float inv = 1.0f / Lt;                                            \
        __hip_bfloat16* dst = ctx + ((size_t)(b * LLEN + (QG))) * DD + h * HDD; \
        const int T = w >> 1;                                                   \
        const int gb = (w & 1) * 2;                                             \
        _Pragma("unroll")                                                       \
        for (int g2 = 0; g2 < 2; ++g2) {                                        \
            const int g = gb + g2;                                              \
            const int rb = T * 16 + 4 * g;                                      \
            float acc4[4] = {0.f, 0.f, 0.f, 0.f};                               \
            _Pragma("unroll")                                                   \
            for (int j = 0; j < 4; ++j) {                                       \
                unsigned a = *reinterpret_cast<const unsigned*>(&oLs[j][lane][rb]);     \
                unsigned c = *reinterpret_cast<const unsigned*>(&oLs[j][lane][rb + 2]); \
                acc4[0] += bfu((ushort)(a & 0xffff));                           \
                acc4[1] += bfu((ushort)(a >> 16));                              \
                acc4[2] += bfu((ushort)(c & 0xffff));                           \
                acc4[3] += bfu((ushort)(c >> 16));                              \
            }                                                                   \
            ushort st4[4];                                                      \
            _Pragma("unroll")                                                   \
            for (int e = 0; e < 4; ++e) st4[e] = f2bf(acc4[e] * inv);           \
            const int d = T * 32 + 8 * g + 4 * hi;                              \
            *reinterpret_cast<ushort4*>(dst + d) =                              \
                *reinterpret_cast<ushort4*>(st4);                               \
        }                                                                       \
    } while (0)

__global__ __launch_bounds__(256) void attn_mfma16_k(const __bf16* __restrict__ Qp,
                                                     const __bf16* __restrict__ Kp,
                                                     const __bf16* __restrict__ Vp,
                                                     __hip_bfloat16* __restrict__ ctx) {
    __shared__ ushort oLs[4][64][34];
    __shared__ float lvL[4][64];

    const int tid  = threadIdx.x;
    const int w    = tid >> 6;
    const int lane = tid & 63;
    const int q32  = lane & 31;
    const int hi   = lane >> 5;

    const int bid = blockIdx.x;
    const int g_  = (bid & 7) * 128 + (bid >> 3);
    const int bh  = g_ >> 5;
    const int ap  = g_ & 31;
    const int qtA = 63 - ap;
    const int qtB = ap;
    const int qgA = qtA * 32 + q32;
    const int qgB = qtB * 32 + q32;

    const __bf16* qbase = Qp + (size_t)bh * (64 * 4 * 512) + lane * 8;
    const __bf16* kbase = Kp + (size_t)bh * (64 * 4 * 512) + lane * 8;
    const __bf16* vbase = Vp + (size_t)bh * (64 * 4 * 512) + lane * 8;

    const int b = bh >> 4, h = bh & 15;

    bf16x8 qf[4];
    f32x16 o0, o1;
    float lsum;

    ATTN_COMPUTE(qtA, qgA);
    ATTN_WRITE_PARTIALS();
    __syncthreads();
    ATTN_MERGE_WRITE(qgA);

    ATTN_COMPUTE(qtB, qgB);
    __syncthreads();
    ATTN_WRITE_PARTIALS();
    __syncthreads();
    ATTN_MERGE_WRITE(qgB);
}

// ---------------------------------------------------------------------------
extern "C" void kernel_launch(void* const* d_in, const int* in_sizes, int n_in,
                              void* d_out, int out_size, void* d_ws, size_t ws_size,
                              hipStream_t stream) {
    const float* x    = (const float*)d_in[0];
    const float* wq_w = (const float*)d_in[1];
    const float* wq_b = (const float*)d_in[2];
    const float* wk_w = (const float*)d_in[3];
    const float* wk_b = (const float*)d_in[4];
    const float* wv_w = (const float*)d_in[5];
    const float* wv_b = (const float*)d_in[6];
    const float* wo_w = (const float*)d_in[7];
    const float* wo_b = (const float*)d_in[8];
    float* out = (float*)d_out;

    const size_t MB = 1024 * 1024;
    char* p = (char*)d_ws;
    __bf16* x16   = (__bf16*)p;            p += 8 * MB;   // [4096][1024]
    __bf16* wqkvt = (__bf16*)p;            p += 6 * MB;   // [3072][1024]
    __bf16* wot   = (__bf16*)p;            p += 2 * MB;   // [1024][1024]
    __hip_bfloat16* qp16 = (__hip_bfloat16*)p; p += 8 * MB;  // packed QP (SC2-scaled)
    __hip_bfloat16* kp16 = (__hip_bfloat16*)p; p += 8 * MB;  // packed KP
    __hip_bfloat16* vp16 = (__hip_bfloat16*)p; p += 8 * MB;  // packed VP
    __hip_bfloat16* ctx16 = (__hip_bfloat16*)p;               // [B][L][D]

    hipLaunchKernelGGL(cvt_x_k, dim3(4096), dim3(256), 0, stream, x, (ushort*)x16);
    hipLaunchKernelGGL(wt_cvt_all_k, dim3(16, 16, 4), dim3(256), 0, stream,
                       wq_w, wk_w, wv_w, wo_w, (ushort*)wqkvt, (ushort*)wot);

    // fused QKV projection + RoPE + Q scale fold + Q/K/V fragment packing
    hipLaunchKernelGGL((gemm_mfma_k<1>), dim3(24, 64), dim3(256), 0, stream,
                       x16, wqkvt, wq_b, wk_b, wv_b, (float*)nullptr, qp16, kp16, vp16);

    // attention (paired-qtile, packed Q/K/V, no-max softmax)
    hipLaunchKernelGGL(attn_mfma16_k, dim3(1024), dim3(256), 0, stream,
                       (const __bf16*)qp16, (const __bf16*)kp16, (const __bf16*)vp16, ctx16);

    // output projection (64x64 tiles, 4 blocks/CU)
    hipLaunchKernelGGL((gemm_mfma_k<0>), dim3(16, 64), dim3(256), 0, stream,
                       (const __bf16*)ctx16, wot, wo_b, (const float*)nullptr, (const float*)nullptr,
                       out, (__hip_bfloat16*)nullptr, (__hip_bfloat16*)nullptr, (__hip_bfloat16*)nullptr);
}

// Round 21
// 102.362 us; speedup vs baseline: 1.1611x; 1.0148x over previous
//
#include <hip/hip_runtime.h>
#include <hip/hip_bf16.h>
#include <float.h>
#include <math.h>

// Problem constants: B=2, L=2048, D=1024, NH=16, HD=64
#define BB  2
#define LLEN 2048
#define DD  1024
#define NHH 16
#define HDD 64
#define MROWS (BB * LLEN)   // 4096

typedef __bf16 bf16x8  __attribute__((ext_vector_type(8)));
typedef float  f32x4   __attribute__((ext_vector_type(4)));
typedef float  f32x16  __attribute__((ext_vector_type(16)));
typedef ushort us8     __attribute__((ext_vector_type(8)));

#define EXP2F(x) __builtin_amdgcn_exp2f(x)   // 1-inst v_exp_f32

static __device__ __forceinline__ ushort f2bf(float f) {
    __hip_bfloat16 h = __float2bfloat16(f);
    return *reinterpret_cast<ushort*>(&h);
}
static __device__ __forceinline__ float bfu(ushort u) {
    unsigned x = (unsigned)u << 16;
    return __uint_as_float(x);
}
static __device__ __forceinline__ unsigned pack2(float a, float b) {
    return (unsigned)f2bf(a) | ((unsigned)f2bf(b) << 16);
}

__device__ __forceinline__ void gload16(const void* g, void* l) {
    __builtin_amdgcn_global_load_lds(
        (const __attribute__((address_space(1))) void*)g,
        (__attribute__((address_space(3))) void*)l, 16, 0, 0);
}

// ---------------------------------------------------------------------------
// x fp32 -> bf16, 4 elems/thread
// ---------------------------------------------------------------------------
__global__ __launch_bounds__(256) void cvt_x_k(const float* __restrict__ in,
                                               ushort* __restrict__ out) {
    int idx = blockIdx.x * 256 + threadIdx.x;
    float4 v = reinterpret_cast<const float4*>(in)[idx];
    ushort4 o;
    o.x = f2bf(v.x); o.y = f2bf(v.y); o.z = f2bf(v.z); o.w = f2bf(v.w);
    reinterpret_cast<ushort4*>(out)[idx] = o;
}

// ---------------------------------------------------------------------------
// All 4 weight transposes+converts in one launch: fp32 [1024][1024] -> bf16 [N][K]
// ---------------------------------------------------------------------------
__global__ __launch_bounds__(256) void wt_cvt_all_k(const float* __restrict__ w0,
                                                    const float* __restrict__ w1,
                                                    const float* __restrict__ w2,
                                                    const float* __restrict__ w3,
                                                    ushort* __restrict__ qkv,
                                                    ushort* __restrict__ wo) {
    __shared__ float T[64][65];
    const int z = blockIdx.z;
    const float* in = (z == 0) ? w0 : (z == 1) ? w1 : (z == 2) ? w2 : w3;
    ushort* out = (z < 3) ? (qkv + (size_t)z * 1024 * DD) : wo;

    const int r0 = blockIdx.y * 64, c0 = blockIdx.x * 64;
    const int tid = threadIdx.x;
    for (int i = tid; i < 64 * 16; i += 256) {
        int r = i >> 4, c4 = (i & 15) * 4;
        float4 v = *reinterpret_cast<const float4*>(&in[(size_t)(r0 + r) * DD + c0 + c4]);
        T[r][c4 + 0] = v.x; T[r][c4 + 1] = v.y; T[r][c4 + 2] = v.z; T[r][c4 + 3] = v.w;
    }
    __syncthreads();
    for (int i = tid; i < 64 * 16; i += 256) {
        int rr = i >> 4, cc4 = (i & 15) * 4;
        ushort4 o;
        o.x = f2bf(T[cc4 + 0][rr]);
        o.y = f2bf(T[cc4 + 1][rr]);
        o.z = f2bf(T[cc4 + 2][rr]);
        o.w = f2bf(T[cc4 + 3][rr]);
        *reinterpret_cast<ushort4*>(&out[(size_t)(c0 + rr) * DD + r0 + cc4]) = o;
    }
}

// ---------------------------------------------------------------------------
// bf16 MFMA GEMM (round-20, passing): small tiles.
//   MODE 1 (QKV): 64x128, grid (24,64); MODE 0 (out): 64x64, grid (16,64).
// ---------------------------------------------------------------------------
template <int MODE>
__global__ __launch_bounds__(256, 6) void gemm_mfma_k(
    const __bf16* __restrict__ A, const __bf16* __restrict__ Bt,
    const float* __restrict__ bias0, const float* __restrict__ bias1,
    const float* __restrict__ bias2,
    float* __restrict__ out_f32,
    __hip_bfloat16* __restrict__ oq, __hip_bfloat16* __restrict__ ok,
    __hip_bfloat16* __restrict__ ov) {
    constexpr int K  = DD;
    constexpr int NF = (MODE == 1) ? 8 : 4;
    constexpr int BN = NF * 16;
    constexpr int SMEMB = (64 + BN) * 64 * 2;
    __shared__ char smem[SMEMB];
    __bf16* As = (__bf16*)smem;
    __bf16* Bs = As + 64 * 64;

    const int tid  = threadIdx.x;
    const int w    = tid >> 6;
    const int lane = tid & 63;
    const int lr   = lane & 15;
    const int lg   = lane >> 4;
    const int bm = blockIdx.y * 64, bn = blockIdx.x * BN;

    const int srow8 = lane >> 3;
    const int schk  = (lane & 7) ^ srow8;
    const __bf16* gA = A  + (size_t)(bm + w * 16 + srow8) * K + schk * 8;
    const __bf16* gB = Bt + (size_t)(bn + w * (NF * 4) + srow8) * K + schk * 8;
    char* ldsA = (char*)As + w * 16 * 128;
    char* ldsB = (char*)Bs + w * (NF * 4) * 128;

    f32x4 acc[NF] = {};
    const int l7 = lr & 7;

    for (int k0 = 0; k0 < K; k0 += 64) {
#pragma unroll
        for (int c = 0; c < 2; ++c)
            gload16(gA + (size_t)(c * 8) * K + k0, ldsA + c * 1024);
#pragma unroll
        for (int c = 0; c < NF / 2; ++c)
            gload16(gB + (size_t)(c * 8) * K + k0, ldsB + c * 1024);
        __syncthreads();
#pragma unroll
        for (int kk = 0; kk < 2; ++kk) {
            const int rchk = ((kk * 4 + lg) ^ l7) << 3;
            bf16x8 a = *reinterpret_cast<const bf16x8*>(As + (w * 16 + lr) * 64 + rchk);
#pragma unroll
            for (int n = 0; n < NF; ++n) {
                bf16x8 b = *reinterpret_cast<const bf16x8*>(Bs + (n * 16 + lr) * 64 + rchk);
                acc[n] = __builtin_amdgcn_mfma_f32_16x16x32_bf16(a, b, acc[n], 0, 0, 0);
            }
        }
        __syncthreads();
    }

    if (MODE == 1) {
        const int seg = bn >> 10;
        const int colbase = bn & 1023;
        const int h0 = colbase >> 6;
        const int b  = bm >> 11;
        const int bmL = bm & 2047;
        if (seg == 2) {
#pragma unroll
            for (int n = 0; n < NF; ++n) {
                const int h  = h0 + (n >> 2);
                const int hd = (n & 3) * 16 + lr;
                const float bv = bias2[colbase + n * 16 + lr];
                const int rowb = bm + w * 16 + lg * 4;
                const int l0 = rowb & 2047;
                ushort4 st;
                st.x = f2bf(acc[n][0] + bv);
                st.y = f2bf(acc[n][1] + bv);
                st.z = f2bf(acc[n][2] + bv);
                st.w = f2bf(acc[n][3] + bv);
                const int bh = b * NHH + h;
                const int t  = l0 >> 5;
                const int j  = ((hd >> 5) << 1) | ((l0 >> 4) & 1);
                const int ln = (hd & 31) + ((l0 >> 3) & 1) * 32;
                const int e0 = l0 & 7;
                size_t base = ((((size_t)bh * 64 + t) * 4 + j) * 64 + ln) * 8 + e0;
                *reinterpret_cast<ushort4*>(&ov[base]) = st;
            }
        } else {
            const float* biasp = (seg == 0) ? bias0 : bias1;
            const float osc = (seg == 0) ? 0.18033688011112042f : 1.0f;
            ushort* LP = (ushort*)smem + w * 2048;
#pragma unroll
            for (int hh = 0; hh < 2; ++hh) {
#pragma unroll
                for (int n2 = 0; n2 < 2; ++n2) {
                    const int nA = hh * 4 + n2, nB = nA + 2;
                    const int d  = n2 * 16 + lr;
                    const float tsd = exp2f((float)d * -0.4152410118609203f);
                    const float bv0 = biasp[colbase + hh * 64 + d];
                    const float bv1 = biasp[colbase + hh * 64 + d + 32];
                    const int c0  = d >> 4;
                    const int hi8 = (d >> 3) & 1;
#pragma unroll
                    for (int i = 0; i < 4; ++i) {
                        const int lw = lg * 4 + i;
                        const int l  = bmL + w * 16 + lw;
                        float s, c;
                        __sincosf((float)l * tsd, &s, &c);
                        const float x0 = acc[nA][i] + bv0;
                        const float x1 = acc[nB][i] + bv1;
                        const int lnL = lw + 16 * hi8;
                        LP[hh * 1024 + (c0 * 32 + lnL) * 8 + (d & 7)] =
                            f2bf((x0 * c - x1 * s) * osc);
                        LP[hh * 1024 + ((c0 + 2) * 32 + lnL) * 8 + (d & 7)] =
                            f2bf((x1 * c + x0 * s) * osc);
                    }
                }
            }
            __syncthreads();
            ushort* dstp = (ushort*)((seg == 0) ? oq : ok);
            const int t   = (bmL >> 5) + (w >> 1);
            const int r0w = (w & 1) * 16;
#pragma unroll
            for (int hh = 0; hh < 2; ++hh) {
                const int bh = b * NHH + h0 + hh;
#pragma unroll
                for (int it = 0; it < 2; ++it) {
                    const int f = it * 64 + lane;
                    const int c = f >> 5, lnL = f & 31;
                    const int ln = r0w + (lnL & 15) + 32 * (lnL >> 4);
                    us8 v = *reinterpret_cast<const us8*>(&LP[hh * 1024 + f * 8]);
                    size_t base = ((((size_t)bh * 64 + t) * 4 + c) * 64 + ln) * 8;
                    *reinterpret_cast<us8*>(&dstp[base]) = v;
                }
            }
        }
    } else {
        float* FP = (float*)smem + w * 1024;
        __syncthreads();
#pragma unroll
        for (int n = 0; n < NF; ++n) {
            const int col = n * 16 + lr;
            const float bv = bias0[bn + col];
#pragma unroll
            for (int i = 0; i < 4; ++i)
                FP[(lg * 4 + i) * 64 + col] = acc[n][i] + bv;
        }
        __syncthreads();
#pragma unroll
        for (int it = 0; it < 4; ++it) {
            const int f = it * 64 + lane;
            const int row16 = f >> 4, cq = f & 15;
            float4 v = *reinterpret_cast<const float4*>(&FP[row16 * 64 + cq * 4]);
            const int row = bm + w * 16 + row16;
            *reinterpret_cast<float4*>(&out_f32[(size_t)row * DD + bn + cq * 4]) = v;
        }
    }
}

// ---------------------------------------------------------------------------
// Flash attention (causal), swapped-operand 32x32 MFMA, packed Q/K/V,
// no-max softmax, bf16 LDS partials. 2048 blocks = ONE qtile per block
// (8 blocks/CU -> ~28 waves/CU vs 16 in the paired form), heavy-first per
// XCD (LPT). 4-way split-KV within block + single merge (proven machinery).
// ---------------------------------------------------------------------------
#define ATTN_LOAD(KF, VF, T0)                                                   \
    do {                                                                        \
        const __bf16* kp_ = kbase + (size_t)(T0) * 2048;                        \
        KF[0] = *reinterpret_cast<const bf16x8*>(kp_);                          \
        KF[1] = *reinterpret_cast<const bf16x8*>(kp_ + 512);                    \
        KF[2] = *reinterpret_cast<const bf16x8*>(kp_ + 1024);                   \
        KF[3] = *reinterpret_cast<const bf16x8*>(kp_ + 1536);                   \
        const __bf16* vp_ = vbase + (size_t)(T0) * 2048;                        \
        VF[0] = *reinterpret_cast<const bf16x8*>(vp_);                          \
        VF[1] = *reinterpret_cast<const bf16x8*>(vp_ + 512);                    \
        VF[2] = *reinterpret_cast<const bf16x8*>(vp_ + 1024);                   \
        VF[3] = *reinterpret_cast<const bf16x8*>(vp_ + 1536);                   \
    } while (0)

#define ATTN_TILE(KF, VF, T0, MASKIT, QG)                                       \
    do {                                                                        \
        f32x16 s_ = {};                                                         \
        __builtin_amdgcn_s_setprio(1);                                          \
        s_ = __builtin_amdgcn_mfma_f32_32x32x16_bf16(KF[0], qf[0], s_, 0, 0, 0);\
        s_ = __builtin_amdgcn_mfma_f32_32x32x16_bf16(KF[1], qf[1], s_, 0, 0, 0);\
        s_ = __builtin_amdgcn_mfma_f32_32x32x16_bf16(KF[2], qf[2], s_, 0, 0, 0);\
        s_ = __builtin_amdgcn_mfma_f32_32x32x16_bf16(KF[3], qf[3], s_, 0, 0, 0);\
        __builtin_amdgcn_s_setprio(0);                                          \
        float p_[16];                                                           \
        const int k0_ = (T0) * 32;                                              \
        if (MASKIT) {                                                           \
            _Pragma("unroll")                                                   \
            for (int i = 0; i < 16; ++i) {                                      \
                int kkg_ = k0_ + (i & 3) + 8 * (i >> 2) + 4 * hi;               \
                p_[i] = (kkg_ <= (QG)) ? EXP2F(s_[i]) : 0.f;                    \
            }                                                                   \
        } else {                                                                \
            _Pragma("unroll")                                                   \
            for (int i = 0; i < 16; ++i) p_[i] = EXP2F(s_[i]);                  \
        }                                                                       \
        _Pragma("unroll")                                                       \
        for (int i = 0; i < 16; ++i) lsum += p_[i];                             \
        unsigned u_[8], x_[8];                                                  \
        _Pragma("unroll")                                                       \
        for (int j = 0; j < 8; ++j)                                             \
            u_[j] = pack2(p_[2 * j], p_[2 * j + 1]);                            \
        _Pragma("unroll")                                                       \
        for (int j = 0; j < 8; ++j)                                             \
            x_[j] = (unsigned)__shfl_xor((int)u_[j], 32);                       \
        union { unsigned d[4]; bf16x8 v; } B1_, B2_;                            \
        if (hi == 0) {                                                          \
            B1_.d[0] = u_[0]; B1_.d[1] = u_[1]; B1_.d[2] = x_[0]; B1_.d[3] = x_[1]; \
            B2_.d[0] = u_[4]; B2_.d[1] = u_[5]; B2_.d[2] = x_[4]; B2_.d[3] = x_[5]; \
        } else {                                                                \
            B1_.d[0] = x_[2]; B1_.d[1] = x_[3]; B1_.d[2] = u_[2]; B1_.d[3] = u_[3]; \
            B2_.d[0] = x_[6]; B2_.d[1] = x_[7]; B2_.d[2] = u_[6]; B2_.d[3] = u_[7]; \
        }                                                                       \
        __builtin_amdgcn_s_setprio(1);                                          \
        o0 = __builtin_amdgcn_mfma_f32_32x32x16_bf16(VF[0], B1_.v, o0, 0, 0, 0);\
        o0 = __builtin_amdgcn_mfma_f32_32x32x16_bf16(VF[1], B2_.v, o0, 0, 0, 0);\
        o1 = __builtin_amdgcn_mfma_f32_32x32x16_bf16(VF[2], B1_.v, o1, 0, 0, 0);\
        o1 = __builtin_amdgcn_mfma_f32_32x32x16_bf16(VF[3], B2_.v, o1, 0, 0, 0);\
        __builtin_amdgcn_s_setprio(0);                                          \
    } while (0)

__global__ __launch_bounds__(256) void attn_mfma17_k(const __bf16* __restrict__ Qp,
                                                     const __bf16* __restrict__ Kp,
                                                     const __bf16* __restrict__ Vp,
                                                     __hip_bfloat16* __restrict__ ctx) {
    __shared__ ushort oLs[4][64][34];   // bf16 partials; stride 34 -> 2-way (free)
    __shared__ float lvL[4][64];

    const int tid  = threadIdx.x;
    const int w    = tid >> 6;
    const int lane = tid & 63;
    const int q32  = lane & 31;
    const int hi   = lane >> 5;

    // XCD swizzle: 2048 blocks; XCD x gets heads [4x,4x+4), heavy qtiles first
    const int bid = blockIdx.x;
    const int g_  = (bid & 7) * 256 + (bid >> 3);
    const int bh  = g_ >> 6;            // 0..31
    const int qt  = 63 - (g_ & 63);     // heavy first (LPT)
    const int qg  = qt * 32 + q32;

    // packed Q/K/V: [bh][64 tiles][4 frags][64 lanes][8 elems]
    const __bf16* qbase = Qp + (size_t)bh * (64 * 4 * 512) + lane * 8;
    const __bf16* kbase = Kp + (size_t)bh * (64 * 4 * 512) + lane * 8;
    const __bf16* vbase = Vp + (size_t)bh * (64 * 4 * 512) + lane * 8;

    const int b = bh >> 4, h = bh & 15;

    bf16x8 qf[4];
    const __bf16* qp_ = qbase + (size_t)qt * 2048;
    qf[0] = *reinterpret_cast<const bf16x8*>(qp_);
    qf[1] = *reinterpret_cast<const bf16x8*>(qp_ + 512);
    qf[2] = *reinterpret_cast<const bf16x8*>(qp_ + 1024);
    qf[3] = *reinterpret_cast<const bf16x8*>(qp_ + 1536);

    f32x16 o0 = {}, o1 = {};
    float lsum = 0.f;

    bf16x8 kf[4], vf[4];
    for (int t = w; t <= qt; t += 4) {
        ATTN_LOAD(kf, vf, t);
        ATTN_TILE(kf, vf, t, t == qt, qg);
    }

    // write bf16 partials
#pragma unroll
    for (int r = 0; r < 16; r += 2) {
        *reinterpret_cast<unsigned*>(&oLs[w][lane][r])      = pack2(o0[r], o0[r + 1]);
        *reinterpret_cast<unsigned*>(&oLs[w][lane][16 + r]) = pack2(o1[r], o1[r + 1]);
    }
    lvL[w][lane] = lsum;
    __syncthreads();

    // merge: wave w handles output regs [w*8, w*8+8)
    float Lt = 0.f;
#pragma unroll
    for (int j = 0; j < 4; ++j)
        Lt += lvL[j][q32] + lvL[j][q32 + 32];
    const float inv = 1.0f / Lt;

    __hip_bfloat16* dst = ctx + ((size_t)(b * LLEN + qg)) * DD + h * HDD;
    const int T = w >> 1;
    const int gb = (w & 1) * 2;
#pragma unroll
    for (int g2 = 0; g2 < 2; ++g2) {
        const int g = gb + g2;
        const int rb = T * 16 + 4 * g;
        float acc4[4] = {0.f, 0.f, 0.f, 0.f};
#pragma unroll
        for (int j = 0; j < 4; ++j) {
            unsigned a = *reinterpret_cast<const unsigned*>(&oLs[j][lane][rb]);
            unsigned c = *reinterpret_cast<const unsigned*>(&oLs[j][lane][rb + 2]);
            acc4[0] += bfu((ushort)(a & 0xffff));
            acc4[1] += bfu((ushort)(a >> 16));
            acc4[2] += bfu((ushort)(c & 0xffff));
            acc4[3] += bfu((ushort)(c >> 16));
        }
        ushort st4[4];
#pragma unroll
        for (int e = 0; e < 4; ++e) st4[e] = f2bf(acc4[e] * inv);
        const int d = T * 32 + 8 * g + 4 * hi;
        *reinterpret_cast<ushort4*>(dst + d) = *reinterpret_cast<ushort4*>(st4);
    }
}

// ---------------------------------------------------------------------------
extern "C" void kernel_launch(void* const* d_in, const int* in_sizes, int n_in,
                              void* d_out, int out_size, void* d_ws, size_t ws_size,
                              hipStream_t stream) {
    const float* x    = (const float*)d_in[0];
    const float* wq_w = (const float*)d_in[1];
    const float* wq_b = (const float*)d_in[2];
    const float* wk_w = (const float*)d_in[3];
    const float* wk_b = (const float*)d_in[4];
    const float* wv_w = (const float*)d_in[5];
    const float* wv_b = (const float*)d_in[6];
    const float* wo_w = (const float*)d_in[7];
    const float* wo_b = (const float*)d_in[8];
    float* out = (float*)d_out;

    const size_t MB = 1024 * 1024;
    char* p = (char*)d_ws;
    __bf16* x16   = (__bf16*)p;            p += 8 * MB;   // [4096][1024]
    __bf16* wqkvt = (__bf16*)p;            p += 6 * MB;   // [3072][1024]
    __bf16* wot   = (__bf16*)p;            p += 2 * MB;   // [1024][1024]
    __hip_bfloat16* qp16 = (__hip_bfloat16*)p; p += 8 * MB;  // packed QP (SC2-scaled)
    __hip_bfloat16* kp16 = (__hip_bfloat16*)p; p += 8 * MB;  // packed KP
    __hip_bfloat16* vp16 = (__hip_bfloat16*)p; p += 8 * MB;  // packed VP
    __hip_bfloat16* ctx16 = (__hip_bfloat16*)p;               // [B][L][D]

    hipLaunchKernelGGL(cvt_x_k, dim3(4096), dim3(256), 0, stream, x, (ushort*)x16);
    hipLaunchKernelGGL(wt_cvt_all_k, dim3(16, 16, 4), dim3(256), 0, stream,
                       wq_w, wk_w, wv_w, wo_w, (ushort*)wqkvt, (ushort*)wot);

    // fused QKV projection + RoPE + Q scale fold + Q/K/V fragment packing
    hipLaunchKernelGGL((gemm_mfma_k<1>), dim3(24, 64), dim3(256), 0, stream,
                       x16, wqkvt, wq_b, wk_b, wv_b, (float*)nullptr, qp16, kp16, vp16);

    // attention (single qtile/block, 2048 blocks, heavy-first, split-KV)
    hipLaunchKernelGGL(attn_mfma17_k, dim3(2048), dim3(256), 0, stream,
                       (const __bf16*)qp16, (const __bf16*)kp16, (const __bf16*)vp16, ctx16);

    // output projection (64x64 tiles)
    hipLaunchKernelGGL((gemm_mfma_k<0>), dim3(16, 64), dim3(256), 0, stream,
                       (const __bf16*)ctx16, wot, wo_b, (const float*)nullptr, (const float*)nullptr,
                       out, (__hip_bfloat16*)nullptr, (__hip_bfloat16*)nullptr, (__hip_bfloat16*)nullptr);
}

// Round 22
// 100.428 us; speedup vs baseline: 1.1835x; 1.0193x over previous
//
#include <hip/hip_runtime.h>
#include <hip/hip_bf16.h>
#include <float.h>
#include <math.h>

// Problem constants: B=2, L=2048, D=1024, NH=16, HD=64
#define BB  2
#define LLEN 2048
#define DD  1024
#define NHH 16
#define HDD 64
#define MROWS (BB * LLEN)   // 4096

typedef __bf16 bf16x8  __attribute__((ext_vector_type(8)));
typedef float  f32x4   __attribute__((ext_vector_type(4)));
typedef float  f32x16  __attribute__((ext_vector_type(16)));
typedef ushort us8     __attribute__((ext_vector_type(8)));

#define EXP2F(x) __builtin_amdgcn_exp2f(x)   // 1-inst v_exp_f32

static __device__ __forceinline__ ushort f2bf(float f) {
    __hip_bfloat16 h = __float2bfloat16(f);
    return *reinterpret_cast<ushort*>(&h);
}
static __device__ __forceinline__ float bfu(ushort u) {
    unsigned x = (unsigned)u << 16;
    return __uint_as_float(x);
}
static __device__ __forceinline__ unsigned pack2(float a, float b) {
    return (unsigned)f2bf(a) | ((unsigned)f2bf(b) << 16);
}

__device__ __forceinline__ void gload16(const void* g, void* l) {
    __builtin_amdgcn_global_load_lds(
        (const __attribute__((address_space(1))) void*)g,
        (__attribute__((address_space(3))) void*)l, 16, 0, 0);
}

// ---------------------------------------------------------------------------
// x fp32 -> bf16, 4 elems/thread
// ---------------------------------------------------------------------------
__global__ __launch_bounds__(256) void cvt_x_k(const float* __restrict__ in,
                                               ushort* __restrict__ out) {
    int idx = blockIdx.x * 256 + threadIdx.x;
    float4 v = reinterpret_cast<const float4*>(in)[idx];
    ushort4 o;
    o.x = f2bf(v.x); o.y = f2bf(v.y); o.z = f2bf(v.z); o.w = f2bf(v.w);
    reinterpret_cast<ushort4*>(out)[idx] = o;
}

// ---------------------------------------------------------------------------
// All 4 weight transposes+converts in one launch: fp32 [1024][1024] -> bf16 [N][K]
// ---------------------------------------------------------------------------
__global__ __launch_bounds__(256) void wt_cvt_all_k(const float* __restrict__ w0,
                                                    const float* __restrict__ w1,
                                                    const float* __restrict__ w2,
                                                    const float* __restrict__ w3,
                                                    ushort* __restrict__ qkv,
                                                    ushort* __restrict__ wo) {
    __shared__ float T[64][65];
    const int z = blockIdx.z;
    const float* in = (z == 0) ? w0 : (z == 1) ? w1 : (z == 2) ? w2 : w3;
    ushort* out = (z < 3) ? (qkv + (size_t)z * 1024 * DD) : wo;

    const int r0 = blockIdx.y * 64, c0 = blockIdx.x * 64;
    const int tid = threadIdx.x;
    for (int i = tid; i < 64 * 16; i += 256) {
        int r = i >> 4, c4 = (i & 15) * 4;
        float4 v = *reinterpret_cast<const float4*>(&in[(size_t)(r0 + r) * DD + c0 + c4]);
        T[r][c4 + 0] = v.x; T[r][c4 + 1] = v.y; T[r][c4 + 2] = v.z; T[r][c4 + 3] = v.w;
    }
    __syncthreads();
    for (int i = tid; i < 64 * 16; i += 256) {
        int rr = i >> 4, cc4 = (i & 15) * 4;
        ushort4 o;
        o.x = f2bf(T[cc4 + 0][rr]);
        o.y = f2bf(T[cc4 + 1][rr]);
        o.z = f2bf(T[cc4 + 2][rr]);
        o.w = f2bf(T[cc4 + 3][rr]);
        *reinterpret_cast<ushort4*>(&out[(size_t)(c0 + rr) * DD + r0 + cc4]) = o;
    }
}

// ---------------------------------------------------------------------------
// bf16 MFMA GEMM: small tiles + 2-PHASE DOUBLE BUFFER (T3 minimum recipe):
// per iteration, issue next K-slice's global_load_lds BEFORE computing the
// current slice, one __syncthreads per iter -> load latency hides under the
// ds_read+MFMA phase instead of being exposed at a drain barrier.
//   MODE 1 (QKV): 64x128 tile, grid (24,64), LDS 48KB (3 blocks/CU).
//   MODE 0 (out): 64x64 tile,  grid (16,64), LDS 32KB (4 blocks/CU).
// (round-17's failure isolated to BK=32 + broken swizzle + sched_barrier
//  pinning; this keeps BK=64, the proven swizzle, and no asm waitcnts.)
// ---------------------------------------------------------------------------
template <int MODE>
__global__ __launch_bounds__(256, 3) void gemm_mfma_k(
    const __bf16* __restrict__ A, const __bf16* __restrict__ Bt,
    const float* __restrict__ bias0, const float* __restrict__ bias1,
    const float* __restrict__ bias2,
    float* __restrict__ out_f32,
    __hip_bfloat16* __restrict__ oq, __hip_bfloat16* __restrict__ ok,
    __hip_bfloat16* __restrict__ ov) {
    constexpr int K  = DD;
    constexpr int NF = (MODE == 1) ? 8 : 4;      // n-frags per wave
    constexpr int BN = NF * 16;                  // tile N: 128 or 64
    constexpr int HALF = (64 + BN) * 64;         // elems per buffer
    __shared__ char smem[2 * HALF * 2];          // 48KB or 32KB
    __bf16* smem_e = (__bf16*)smem;

    const int tid  = threadIdx.x;
    const int w    = tid >> 6;
    const int lane = tid & 63;
    const int lr   = lane & 15;
    const int lg   = lane >> 4;
    const int bm = blockIdx.y * 64, bn = blockIdx.x * BN;

    const int srow8 = lane >> 3;
    const int schk  = (lane & 7) ^ srow8;        // pre-swizzled src chunk
    const __bf16* gA = A  + (size_t)(bm + w * 16 + srow8) * K + schk * 8;
    const __bf16* gB = Bt + (size_t)(bn + w * (NF * 4) + srow8) * K + schk * 8;

    f32x4 acc[NF] = {};
    const int l7 = lr & 7;

    auto STAGE = [&](int buf, int k0) {
        __bf16* base = smem_e + buf * HALF;
        char* lA = (char*)base + w * 16 * 128;
        char* lB = (char*)(base + 4096) + w * (NF * 4) * 128;
#pragma unroll
        for (int c = 0; c < 2; ++c)
            gload16(gA + (size_t)(c * 8) * K + k0, lA + c * 1024);
#pragma unroll
        for (int c = 0; c < NF / 2; ++c)
            gload16(gB + (size_t)(c * 8) * K + k0, lB + c * 1024);
    };

    STAGE(0, 0);
    __syncthreads();
    for (int i = 0; i < 16; ++i) {
        if (i < 15) STAGE((i + 1) & 1, (i + 1) * 64);   // issue-early prefetch
        const __bf16* As_ = smem_e + (i & 1) * HALF;
        const __bf16* Bs_ = As_ + 4096;
#pragma unroll
        for (int kk = 0; kk < 2; ++kk) {
            const int rchk = ((kk * 4 + lg) ^ l7) << 3;
            bf16x8 a = *reinterpret_cast<const bf16x8*>(As_ + (w * 16 + lr) * 64 + rchk);
#pragma unroll
            for (int n = 0; n < NF; ++n) {
                bf16x8 b = *reinterpret_cast<const bf16x8*>(Bs_ + (n * 16 + lr) * 64 + rchk);
                acc[n] = __builtin_amdgcn_mfma_f32_16x16x32_bf16(a, b, acc[n], 0, 0, 0);
            }
        }
        __syncthreads();   // drains prefetch (had full compute phase) + buffer reuse
    }

    if (MODE == 1) {
        const int seg = bn >> 10;
        const int colbase = bn & 1023;
        const int h0 = colbase >> 6;
        const int b  = bm >> 11;
        const int bmL = bm & 2047;
        if (seg == 2) {
#pragma unroll
            for (int n = 0; n < NF; ++n) {
                const int h  = h0 + (n >> 2);
                const int hd = (n & 3) * 16 + lr;
                const float bv = bias2[colbase + n * 16 + lr];
                const int rowb = bm + w * 16 + lg * 4;
                const int l0 = rowb & 2047;
                ushort4 st;
                st.x = f2bf(acc[n][0] + bv);
                st.y = f2bf(acc[n][1] + bv);
                st.z = f2bf(acc[n][2] + bv);
                st.w = f2bf(acc[n][3] + bv);
                const int bh = b * NHH + h;
                const int t  = l0 >> 5;
                const int j  = ((hd >> 5) << 1) | ((l0 >> 4) & 1);
                const int ln = (hd & 31) + ((l0 >> 3) & 1) * 32;
                const int e0 = l0 & 7;
                size_t base = ((((size_t)bh * 64 + t) * 4 + j) * 64 + ln) * 8 + e0;
                *reinterpret_cast<ushort4*>(&ov[base]) = st;
            }
        } else {
            const float* biasp = (seg == 0) ? bias0 : bias1;
            const float osc = (seg == 0) ? 0.18033688011112042f : 1.0f;
            ushort* LP = (ushort*)smem + w * 2048;
#pragma unroll
            for (int hh = 0; hh < 2; ++hh) {
#pragma unroll
                for (int n2 = 0; n2 < 2; ++n2) {
                    const int nA = hh * 4 + n2, nB = nA + 2;
                    const int d  = n2 * 16 + lr;
                    const float tsd = exp2f((float)d * -0.4152410118609203f);
                    const float bv0 = biasp[colbase + hh * 64 + d];
                    const float bv1 = biasp[colbase + hh * 64 + d + 32];
                    const int c0  = d >> 4;
                    const int hi8 = (d >> 3) & 1;
#pragma unroll
                    for (int i = 0; i < 4; ++i) {
                        const int lw = lg * 4 + i;
                        const int l  = bmL + w * 16 + lw;
                        float s, c;
                        __sincosf((float)l * tsd, &s, &c);
                        const float x0 = acc[nA][i] + bv0;
                        const float x1 = acc[nB][i] + bv1;
                        const int lnL = lw + 16 * hi8;
                        LP[hh * 1024 + (c0 * 32 + lnL) * 8 + (d & 7)] =
                            f2bf((x0 * c - x1 * s) * osc);
                        LP[hh * 1024 + ((c0 + 2) * 32 + lnL) * 8 + (d & 7)] =
                            f2bf((x1 * c + x0 * s) * osc);
                    }
                }
            }
            __syncthreads();
            ushort* dstp = (ushort*)((seg == 0) ? oq : ok);
            const int t   = (bmL >> 5) + (w >> 1);
            const int r0w = (w & 1) * 16;
#pragma unroll
            for (int hh = 0; hh < 2; ++hh) {
                const int bh = b * NHH + h0 + hh;
#pragma unroll
                for (int it = 0; it < 2; ++it) {
                    const int f = it * 64 + lane;
                    const int c = f >> 5, lnL = f & 31;
                    const int ln = r0w + (lnL & 15) + 32 * (lnL >> 4);
                    us8 v = *reinterpret_cast<const us8*>(&LP[hh * 1024 + f * 8]);
                    size_t base = ((((size_t)bh * 64 + t) * 4 + c) * 64 + ln) * 8;
                    *reinterpret_cast<us8*>(&dstp[base]) = v;
                }
            }
        }
    } else {
        float* FP = (float*)smem + w * 1024;
        __syncthreads();
#pragma unroll
        for (int n = 0; n < NF; ++n) {
            const int col = n * 16 + lr;
            const float bv = bias0[bn + col];
#pragma unroll
            for (int i = 0; i < 4; ++i)
                FP[(lg * 4 + i) * 64 + col] = acc[n][i] + bv;
        }
        __syncthreads();
#pragma unroll
        for (int it = 0; it < 4; ++it) {
            const int f = it * 64 + lane;
            const int row16 = f >> 4, cq = f & 15;
            float4 v = *reinterpret_cast<const float4*>(&FP[row16 * 64 + cq * 4]);
            const int row = bm + w * 16 + row16;
            *reinterpret_cast<float4*>(&out_f32[(size_t)row * DD + bn + cq * 4]) = v;
        }
    }
}

// ---------------------------------------------------------------------------
// Flash attention (causal), swapped-operand 32x32 MFMA, packed Q/K/V,
// no-max softmax, bf16 LDS partials. 2048 blocks = one qtile per block,
// heavy-first per XCD (LPT). (round-21, passing)
// ---------------------------------------------------------------------------
#define ATTN_LOAD(KF, VF, T0)                                                   \
    do {                                                                        \
        const __bf16* kp_ = kbase + (size_t)(T0) * 2048;                        \
        KF[0] = *reinterpret_cast<const bf16x8*>(kp_);                          \
        KF[1] = *reinterpret_cast<const bf16x8*>(kp_ + 512);                    \
        KF[2] = *reinterpret_cast<const bf16x8*>(kp_ + 1024);                   \
        KF[3] = *reinterpret_cast<const bf16x8*>(kp_ + 1536);                   \
        const __bf16* vp_ = vbase + (size_t)(T0) * 2048;                        \
        VF[0] = *reinterpret_cast<const bf16x8*>(vp_);                          \
        VF[1] = *reinterpret_cast<const bf16x8*>(vp_ + 512);                    \
        VF[2] = *reinterpret_cast<const bf16x8*>(vp_ + 1024);                   \
        VF[3] = *reinterpret_cast<const bf16x8*>(vp_ + 1536);                   \
    } while (0)

#define ATTN_TILE(KF, VF, T0, MASKIT, QG)                                       \
    do {                                                                        \
        f32x16 s_ = {};                                                         \
        __builtin_amdgcn_s_setprio(1);                                          \
        s_ = __builtin_amdgcn_mfma_f32_32x32x16_bf16(KF[0], qf[0], s_, 0, 0, 0);\
        s_ = __builtin_amdgcn_mfma_f32_32x32x16_bf16(KF[1], qf[1], s_, 0, 0, 0);\
        s_ = __builtin_amdgcn_mfma_f32_32x32x16_bf16(KF[2], qf[2], s_, 0, 0, 0);\
        s_ = __builtin_amdgcn_mfma_f32_32x32x16_bf16(KF[3], qf[3], s_, 0, 0, 0);\
        __builtin_amdgcn_s_setprio(0);                                          \
        float p_[16];                                                           \
        const int k0_ = (T0) * 32;                                              \
        if (MASKIT) {                                                           \
            _Pragma("unroll")                                                   \
            for (int i = 0; i < 16; ++i) {                                      \
                int kkg_ = k0_ + (i & 3) + 8 * (i >> 2) + 4 * hi;               \
                p_[i] = (kkg_ <= (QG)) ? EXP2F(s_[i]) : 0.f;                    \
            }                                                                   \
        } else {                                                                \
            _Pragma("unroll")                                                   \
            for (int i = 0; i < 16; ++i) p_[i] = EXP2F(s_[i]);                  \
        }                                                                       \
        _Pragma("unroll")                                                       \
        for (int i = 0; i < 16; ++i) lsum += p_[i];                             \
        unsigned u_[8], x_[8];                                                  \
        _Pragma("unroll")                                                       \
        for (int j = 0; j < 8; ++j)                                             \
            u_[j] = pack2(p_[2 * j], p_[2 * j + 1]);                            \
        _Pragma("unroll")                                                       \
        for (int j = 0; j < 8; ++j)                                             \
            x_[j] = (unsigned)__shfl_xor((int)u_[j], 32);                       \
        union { unsigned d[4]; bf16x8 v; } B1_, B2_;                            \
        if (hi == 0) {                                                          \
            B1_.d[0] = u_[0]; B1_.d[1] = u_[1]; B1_.d[2] = x_[0]; B1_.d[3] = x_[1]; \
            B2_.d[0] = u_[4]; B2_.d[1] = u_[5]; B2_.d[2] = x_[4]; B2_.d[3] = x_[5]; \
        } else {                                                                \
            B1_.d[0] = x_[2]; B1_.d[1] = x_[3]; B1_.d[2] = u_[2]; B1_.d[3] = u_[3]; \
            B2_.d[0] = x_[6]; B2_.d[1] = x_[7]; B2_.d[2] = u_[6]; B2_.d[3] = u_[7]; \
        }                                                                       \
        __builtin_amdgcn_s_setprio(1);                                          \
        o0 = __builtin_amdgcn_mfma_f32_32x32x16_bf16(VF[0], B1_.v, o0, 0, 0, 0);\
        o0 = __builtin_amdgcn_mfma_f32_32x32x16_bf16(VF[1], B2_.v, o0, 0, 0, 0);\
        o1 = __builtin_amdgcn_mfma_f32_32x32x16_bf16(VF[2], B1_.v, o1, 0, 0, 0);\
        o1 = __builtin_amdgcn_mfma_f32_32x32x16_bf16(VF[3], B2_.v, o1, 0, 0, 0);\
        __builtin_amdgcn_s_setprio(0);                                          \
    } while (0)

__global__ __launch_bounds__(256) void attn_mfma17_k(const __bf16* __restrict__ Qp,
                                                     const __bf16* __restrict__ Kp,
                                                     const __bf16* __restrict__ Vp,
                                                     __hip_bfloat16* __restrict__ ctx) {
    __shared__ ushort oLs[4][64][34];
    __shared__ float lvL[4][64];

    const int tid  = threadIdx.x;
    const int w    = tid >> 6;
    const int lane = tid & 63;
    const int q32  = lane & 31;
    const int hi   = lane >> 5;

    const int bid = blockIdx.x;
    const int g_  = (bid & 7) * 256 + (bid >> 3);
    const int bh  = g_ >> 6;
    const int qt  = 63 - (g_ & 63);
    const int qg  = qt * 32 + q32;

    const __bf16* qbase = Qp + (size_t)bh * (64 * 4 * 512) + lane * 8;
    const __bf16* kbase = Kp + (size_t)bh * (64 * 4 * 512) + lane * 8;
    const __bf16* vbase = Vp + (size_t)bh * (64 * 4 * 512) + lane * 8;

    const int b = bh >> 4, h = bh & 15;

    bf16x8 qf[4];
    const __bf16* qp_ = qbase + (size_t)qt * 2048;
    qf[0] = *reinterpret_cast<const bf16x8*>(qp_);
    qf[1] = *reinterpret_cast<const bf16x8*>(qp_ + 512);
    qf[2] = *reinterpret_cast<const bf16x8*>(qp_ + 1024);
    qf[3] = *reinterpret_cast<const bf16x8*>(qp_ + 1536);

    f32x16 o0 = {}, o1 = {};
    float lsum = 0.f;

    bf16x8 kf[4], vf[4];
    for (int t = w; t <= qt; t += 4) {
        ATTN_LOAD(kf, vf, t);
        ATTN_TILE(kf, vf, t, t == qt, qg);
    }

#pragma unroll
    for (int r = 0; r < 16; r += 2) {
        *reinterpret_cast<unsigned*>(&oLs[w][lane][r])      = pack2(o0[r], o0[r + 1]);
        *reinterpret_cast<unsigned*>(&oLs[w][lane][16 + r]) = pack2(o1[r], o1[r + 1]);
    }
    lvL[w][lane] = lsum;
    __syncthreads();

    float Lt = 0.f;
#pragma unroll
    for (int j = 0; j < 4; ++j)
        Lt += lvL[j][q32] + lvL[j][q32 + 32];
    const float inv = 1.0f / Lt;

    __hip_bfloat16* dst = ctx + ((size_t)(b * LLEN + qg)) * DD + h * HDD;
    const int T = w >> 1;
    const int gb = (w & 1) * 2;
#pragma unroll
    for (int g2 = 0; g2 < 2; ++g2) {
        const int g = gb + g2;
        const int rb = T * 16 + 4 * g;
        float acc4[4] = {0.f, 0.f, 0.f, 0.f};
#pragma unroll
        for (int j = 0; j < 4; ++j) {
            unsigned a = *reinterpret_cast<const unsigned*>(&oLs[j][lane][rb]);
            unsigned c = *reinterpret_cast<const unsigned*>(&oLs[j][lane][rb + 2]);
            acc4[0] += bfu((ushort)(a & 0xffff));
            acc4[1] += bfu((ushort)(a >> 16));
            acc4[2] += bfu((ushort)(c & 0xffff));
            acc4[3] += bfu((ushort)(c >> 16));
        }
        ushort st4[4];
#pragma unroll
        for (int e = 0; e < 4; ++e) st4[e] = f2bf(acc4[e] * inv);
        const int d = T * 32 + 8 * g + 4 * hi;
        *reinterpret_cast<ushort4*>(dst + d) = *reinterpret_cast<ushort4*>(st4);
    }
}

// ---------------------------------------------------------------------------
extern "C" void kernel_launch(void* const* d_in, const int* in_sizes, int n_in,
                              void* d_out, int out_size, void* d_ws, size_t ws_size,
                              hipStream_t stream) {
    const float* x    = (const float*)d_in[0];
    const float* wq_w = (const float*)d_in[1];
    const float* wq_b = (const float*)d_in[2];
    const float* wk_w = (const float*)d_in[3];
    const float* wk_b = (const float*)d_in[4];
    const float* wv_w = (const float*)d_in[5];
    const float* wv_b = (const float*)d_in[6];
    const float* wo_w = (const float*)d_in[7];
    const float* wo_b = (const float*)d_in[8];
    float* out = (float*)d_out;

    const size_t MB = 1024 * 1024;
    char* p = (char*)d_ws;
    __bf16* x16   = (__bf16*)p;            p += 8 * MB;   // [4096][1024]
    __bf16* wqkvt = (__bf16*)p;            p += 6 * MB;   // [3072][1024]
    __bf16* wot   = (__bf16*)p;            p += 2 * MB;   // [1024][1024]
    __hip_bfloat16* qp16 = (__hip_bfloat16*)p; p += 8 * MB;  // packed QP (SC2-scaled)
    __hip_bfloat16* kp16 = (__hip_bfloat16*)p; p += 8 * MB;  // packed KP
    __hip_bfloat16* vp16 = (__hip_bfloat16*)p; p += 8 * MB;  // packed VP
    __hip_bfloat16* ctx16 = (__hip_bfloat16*)p;               // [B][L][D]

    hipLaunchKernelGGL(cvt_x_k, dim3(4096), dim3(256), 0, stream, x, (ushort*)x16);
    hipLaunchKernelGGL(wt_cvt_all_k, dim3(16, 16, 4), dim3(256), 0, stream,
                       wq_w, wk_w, wv_w, wo_w, (ushort*)wqkvt, (ushort*)wot);

    // fused QKV projection + RoPE + Q scale fold + Q/K/V fragment packing
    hipLaunchKernelGGL((gemm_mfma_k<1>), dim3(24, 64), dim3(256), 0, stream,
                       x16, wqkvt, wq_b, wk_b, wv_b, (float*)nullptr, qp16, kp16, vp16);

    // attention (single qtile/block, 2048 blocks, heavy-first, split-KV)
    hipLaunchKernelGGL(attn_mfma17_k, dim3(2048), dim3(256), 0, stream,
                       (const __bf16*)qp16, (const __bf16*)kp16, (const __bf16*)vp16, ctx16);

    // output projection (64x64 tiles, 2-phase dbuf)
    hipLaunchKernelGGL((gemm_mfma_k<0>), dim3(16, 64), dim3(256), 0, stream,
                       (const __bf16*)ctx16, wot, wo_b, (const float*)nullptr, (const float*)nullptr,
                       out, (__hip_bfloat16*)nullptr, (__hip_bfloat16*)nullptr, (__hip_bfloat16*)nullptr);
}